// Round 7
// baseline (9817.625 us; speedup 1.0000x reference)
//
#include <hip/hip_runtime.h>
#include <hip/hip_cooperative_groups.h>
#include <math.h>

// ---------------------------------------------------------------------------
// WorldModel RSSM forward losses — R7.
// R6 failed: Stage-B block mapping bug (bx up to 47 but kernel body computes
// all 3 gates per block, so j must stay <1024 -> OOB H writes). Fixed to
// blockIdx.x<64, bx=&15, by=>>4. Stages refactored into __device__ bodies
// shared by the cooperative group kernel AND standalone per-step kernels;
// host falls back to standalone launches if hipLaunchCooperativeKernel errs.
// ---------------------------------------------------------------------------

namespace cg = cooperative_groups;

namespace {

typedef unsigned short ushort;
typedef __attribute__((ext_vector_type(8))) short short8;   // 8 bf16 in 4 VGPRs
typedef __attribute__((ext_vector_type(4))) float f32x4;

constexpr int TSTEPS = 63;
constexpr int NB     = 256;
constexpr int NACT   = 32;
constexpr int NROWS  = TSTEPS * NB;   // 16128
constexpr int TGRP   = 7;
constexpr int NGRP   = 9;
constexpr int GROWS  = TGRP * NB;     // 1792 = 28*64

// ---- workspace layout (floats) --------------------------------------------
constexpr size_t OFF_POSTE = 0;                                     // f32 16128x512
constexpr size_t OFF_E1C   = OFF_POSTE + (size_t)NROWS * 512;       // u16 1792x1024
constexpr size_t OFF_EMBC  = OFF_E1C + (size_t)GROWS * 1024 / 2;    // u16 1792x1024
constexpr size_t OFF_FEATC = OFF_EMBC + (size_t)GROWS * 1024 / 2;   // u16 1792x1280
constexpr size_t OFF_DR1C  = OFF_FEATC + (size_t)GROWS * 1280 / 2;  // u16 1792x2048
constexpr size_t OFF_WHT   = OFF_DR1C + (size_t)GROWS * 2048 / 2;   // u16 4096x1024
constexpr size_t OFF_WIHT  = OFF_WHT + (size_t)4096 * 1024 / 2;     // u16 3072x288
constexpr size_t OFF_WDRT  = OFF_WIHT + (size_t)3072 * 288 / 2;     // u16 2048x1280
constexpr size_t OFF_E1T   = OFF_WDRT + (size_t)2048 * 1280 / 2;    // u16 1024x512
constexpr size_t OFF_E2T   = OFF_E1T + (size_t)1024 * 512 / 2;      // u16 1024x1024
constexpr size_t OFF_PET   = OFF_E2T + (size_t)1024 * 1024 / 2;     // u16 512x1024
constexpr size_t OFF_DW2T  = OFF_PET + (size_t)512 * 1024 / 2;      // u16 512x1024
constexpr size_t OFF_BDR   = OFF_DW2T + (size_t)512 * 1024 / 2;     // f32 2048
constexpr size_t OFF_G     = OFF_BDR + 2048;                        // f32 256x3072
constexpr size_t OFF_H     = OFF_G + (size_t)NB * 3072;             // f32 256x1024
constexpr size_t OFF_HB    = OFF_H + (size_t)NB * 1024;             // u16 256x1024
constexpr size_t OFF_ACC   = OFF_HB + (size_t)NB * 1024 / 2;        // f32 16
constexpr size_t OFF_XBUF  = OFF_ACC + 16;                          // u16 256x288

__device__ __forceinline__ ushort f2bf(float f) {
  unsigned int u = __float_as_uint(f);
  unsigned int r = (u + 0x7fffu + ((u >> 16) & 1u)) >> 16;
  return (ushort)r;
}
__device__ __forceinline__ float bf2f(ushort u) {
  return __uint_as_float((unsigned int)u << 16);
}

__global__ void zero_kernel(float* p, int n) {
  int i = blockIdx.x * 256 + threadIdx.x;
  if (i < n) p[i] = 0.f;
}

__global__ void f2bf_kernel(const float* __restrict__ in, ushort* __restrict__ out, int n) {
  int i = blockIdx.x * 256 + threadIdx.x;
  if (i < n) out[i] = f2bf(in[i]);
}

// WHT[n][k]. n<1024: latent-permuted — quad q=(n>>4)&3 selects pm/pl/qm/ql,
// s = (n>>6)*16 + (n&15). n>=1024: whh[n-1024][k].
__global__ void build_wht(const float* __restrict__ prior_w, const float* __restrict__ post_w,
                          const float* __restrict__ whh, ushort* __restrict__ out) {
  int idx = blockIdx.x * 256 + threadIdx.x;  // 4096*1024
  int n = idx >> 10, k = idx & 1023;
  float v;
  if (n < 1024) {
    int q = (n >> 4) & 3;
    int s = ((n >> 6) << 4) | (n & 15);
    v = (q == 0) ? prior_w[k * 512 + s]
      : (q == 1) ? prior_w[k * 512 + 256 + s]
      : (q == 2) ? post_w[k * 512 + s]
                 : post_w[k * 512 + 256 + s];
  } else {
    v = whh[(size_t)(n - 1024) * 1024 + k];
  }
  out[idx] = f2bf(v);
}

// out[c*ldo + r] = bf16(in[r*ldi + c]); grid (C/32, R/32)
__global__ void trans_conv(const float* __restrict__ in, ushort* __restrict__ out,
                           int ldi, int ldo) {
  __shared__ float tile[32][33];
  int r0 = blockIdx.y * 32, c0 = blockIdx.x * 32;
  int tx = threadIdx.x & 31, ty = threadIdx.x >> 5;
#pragma unroll
  for (int p = 0; p < 4; ++p)
    tile[ty + p * 8][tx] = in[(size_t)(r0 + ty + p * 8) * ldi + c0 + tx];
  __syncthreads();
#pragma unroll
  for (int p = 0; p < 4; ++p)
    out[(size_t)(c0 + ty + p * 8) * ldo + r0 + tx] = f2bf(tile[tx][ty + p * 8]);
}

__global__ void build_bdr(const float* __restrict__ dec_b1, const float* __restrict__ rew_b1,
                          float* __restrict__ bdr) {
  int i = blockIdx.x * 256 + threadIdx.x;  // 2048
  bdr[i] = (i < 1024) ? dec_b1[i] : rew_b1[i - 1024];
}

// ---------------------------------------------------------------------------
// Phase A/C bf16 GEMM: C[M,N] = A @ B; A bf16 [M][K], BT bf16 [N][K].
// 64x64 tile, 4 waves, BK=32, LDS stride 40.
// EPI: 1 = +bias, relu, store bf16; 2 = +bias, store f32.
// ---------------------------------------------------------------------------
template <int EPI>
__global__ __launch_bounds__(256) void gemm_bf16(
    const ushort* __restrict__ A, const ushort* __restrict__ BT,
    const float* __restrict__ bias, void* __restrict__ Cv,
    int K, int lda, int ldb, int ldc) {
  __shared__ __align__(16) ushort As[64 * 40];
  __shared__ __align__(16) ushort Bs[64 * 40];
  int tid = threadIdx.x;
  int wave = tid >> 6, lane = tid & 63;
  int quad = lane >> 4, l15 = lane & 15;
  int m0 = blockIdx.y * 64, n0 = blockIdx.x * 64;
  int sr = tid >> 2, sc = (tid & 3) * 8;
  f32x4 acc[4] = {};
  for (int k0 = 0; k0 < K; k0 += 32) {
    *(int4*)&As[sr * 40 + sc] = *(const int4*)(A + (size_t)(m0 + sr) * lda + k0 + sc);
    *(int4*)&Bs[sr * 40 + sc] = *(const int4*)(BT + (size_t)(n0 + sr) * ldb + k0 + sc);
    __syncthreads();
    short8 a = *(const short8*)&As[(wave * 16 + l15) * 40 + quad * 8];
#pragma unroll
    for (int c = 0; c < 4; ++c) {
      short8 b = *(const short8*)&Bs[(c * 16 + l15) * 40 + quad * 8];
      acc[c] = __builtin_amdgcn_mfma_f32_16x16x32_bf16(a, b, acc[c], 0, 0, 0);
    }
    __syncthreads();
  }
#pragma unroll
  for (int c = 0; c < 4; ++c) {
#pragma unroll
    for (int r = 0; r < 4; ++r) {
      size_t row = m0 + wave * 16 + quad * 4 + r;
      int col = n0 + c * 16 + l15;
      float v = acc[c][r] + bias[col];
      if (EPI == 1) v = fmaxf(v, 0.f);
      if (EPI == 1) ((ushort*)Cv)[row * ldc + col] = f2bf(v);
      else ((float*)Cv)[row * ldc + col] = v;
    }
  }
}

// Encoder layer 1 with fused f32->bf16 A staging. A = obs f32 [M][512],
// BT = E1T [1024][512]. M=1792, N=1024, K=512. grid (16, 28). relu, bf16 out.
__global__ __launch_bounds__(256) void gemm_obs(
    const float* __restrict__ A, const ushort* __restrict__ BT,
    const float* __restrict__ bias, ushort* __restrict__ C) {
  __shared__ __align__(16) ushort As[64 * 40];
  __shared__ __align__(16) ushort Bs[64 * 40];
  int tid = threadIdx.x;
  int wave = tid >> 6, lane = tid & 63;
  int quad = lane >> 4, l15 = lane & 15;
  int m0 = blockIdx.y * 64, n0 = blockIdx.x * 64;
  int sr = tid >> 2, sc = (tid & 3) * 8;
  f32x4 acc[4] = {};
  for (int k0 = 0; k0 < 512; k0 += 32) {
    float4 f0 = *(const float4*)(A + (size_t)(m0 + sr) * 512 + k0 + sc);
    float4 f1 = *(const float4*)(A + (size_t)(m0 + sr) * 512 + k0 + sc + 4);
    union { int4 v; ushort u[8]; } cvt;
    cvt.u[0] = f2bf(f0.x); cvt.u[1] = f2bf(f0.y); cvt.u[2] = f2bf(f0.z); cvt.u[3] = f2bf(f0.w);
    cvt.u[4] = f2bf(f1.x); cvt.u[5] = f2bf(f1.y); cvt.u[6] = f2bf(f1.z); cvt.u[7] = f2bf(f1.w);
    *(int4*)&As[sr * 40 + sc] = cvt.v;
    *(int4*)&Bs[sr * 40 + sc] = *(const int4*)(BT + (size_t)(n0 + sr) * 512 + k0 + sc);
    __syncthreads();
    short8 a = *(const short8*)&As[(wave * 16 + l15) * 40 + quad * 8];
#pragma unroll
    for (int c = 0; c < 4; ++c) {
      short8 b = *(const short8*)&Bs[(c * 16 + l15) * 40 + quad * 8];
      acc[c] = __builtin_amdgcn_mfma_f32_16x16x32_bf16(a, b, acc[c], 0, 0, 0);
    }
    __syncthreads();
  }
#pragma unroll
  for (int c = 0; c < 4; ++c) {
#pragma unroll
    for (int r = 0; r < 4; ++r) {
      size_t row = m0 + wave * 16 + quad * 4 + r;
      int col = n0 + c * 16 + l15;
      float v = fmaxf(acc[c][r] + bias[col], 0.f);
      C[row * 1024 + col] = f2bf(v);
    }
  }
}

// ---------------------------------------------------------------------------
// Stage A body: one 64x64 tile of G = HB @ WHT (M=256,N=4096,K=1024), BK=64,
// register prefetch. bx in [0,64): bx<16 -> latent-permuted cols, fused z/KL
// epilogue; else store gh to G [256][3072] f32. by in [0,4).
// Needs smem >= 2*64*72 ushorts.
// ---------------------------------------------------------------------------
__device__ __forceinline__ void stage_a_body(
    int t, int tt, int bx, int by, ushort* smem,
    const ushort* __restrict__ HB, const ushort* __restrict__ WHT,
    const float* __restrict__ prior_b, const float* __restrict__ poste,
    const float* __restrict__ eps, const float* __restrict__ actions,
    float* __restrict__ G, ushort* __restrict__ xbuf,
    ushort* __restrict__ featc, float* __restrict__ acc_kl) {
  ushort* As = smem;            // 64x72
  ushort* Bs = smem + 64 * 72;  // 64x72
  int tid = threadIdx.x;
  int wave = tid >> 6, lane = tid & 63;
  int quad = lane >> 4, l15 = lane & 15;
  int m0 = by * 64, n0 = bx * 64;
  int sr = tid >> 2, sc = (tid & 3) * 16;
  const ushort* agp = HB + (size_t)(m0 + sr) * 1024 + sc;
  const ushort* bgp = WHT + (size_t)(n0 + sr) * 1024 + sc;
  int4 a0 = *(const int4*)agp, a1 = *(const int4*)(agp + 8);
  int4 b0 = *(const int4*)bgp, b1 = *(const int4*)(bgp + 8);
  f32x4 acc[4] = {};
  for (int k0 = 0;;) {
    *(int4*)&As[sr * 72 + sc] = a0; *(int4*)&As[sr * 72 + sc + 8] = a1;
    *(int4*)&Bs[sr * 72 + sc] = b0; *(int4*)&Bs[sr * 72 + sc + 8] = b1;
    __syncthreads();
    int kn = k0 + 64;
    if (kn < 1024) {
      a0 = *(const int4*)(agp + kn); a1 = *(const int4*)(agp + kn + 8);
      b0 = *(const int4*)(bgp + kn); b1 = *(const int4*)(bgp + kn + 8);
    }
#pragma unroll
    for (int kk = 0; kk < 2; ++kk) {
      short8 a = *(const short8*)&As[(wave * 16 + l15) * 72 + kk * 32 + quad * 8];
#pragma unroll
      for (int c = 0; c < 4; ++c) {
        short8 b = *(const short8*)&Bs[(c * 16 + l15) * 72 + kk * 32 + quad * 8];
        acc[c] = __builtin_amdgcn_mfma_f32_16x16x32_bf16(a, b, acc[c], 0, 0, 0);
      }
    }
    k0 = kn;
    if (k0 >= 1024) break;
    __syncthreads();
  }
  if (bx < 16) {
    // latent epilogue: acc[0..3] = pm,pl,qm,ql for s = bx*16 + l15
    int s = (n0 >> 2) + l15;
    float kl_sum = 0.f;
#pragma unroll
    for (int r = 0; r < 4; ++r) {
      int b = m0 + wave * 16 + quad * 4 + r;
      size_t row = (size_t)t * NB + b;
      float pm = acc[0][r] + prior_b[s];
      float pl = acc[1][r] + prior_b[256 + s];
      float qm = acc[2][r] + poste[row * 512 + s];
      float ql = acc[3][r] + poste[row * 512 + 256 + s];
      float e = eps[row * 256 + s];
      float z = qm + e * expf(ql);
      xbuf[b * 288 + s] = f2bf(z);
      featc[(size_t)(tt * NB + b) * 1280 + 1024 + s] = f2bf(z);
      if (s < NACT) xbuf[b * 288 + 256 + s] = f2bf(actions[row * NACT + s]);
      float vq = expf(2.f * ql), vp = expf(2.f * pl);
      float dm = qm - pm;
      kl_sum += pl - ql + (vq + dm * dm) / (vp + 1e-8f) - 1.f;
    }
    for (int off = 32; off > 0; off >>= 1) kl_sum += __shfl_down(kl_sum, off);
    if (lane == 0) atomicAdd(acc_kl, 0.5f * kl_sum);
  } else {
    int ng = n0 - 1024;
#pragma unroll
    for (int c = 0; c < 4; ++c)
#pragma unroll
      for (int r = 0; r < 4; ++r) {
        int b = m0 + wave * 16 + quad * 4 + r;
        G[(size_t)b * 3072 + ng + c * 16 + l15] = acc[c][r];
      }
  }
}

// ---------------------------------------------------------------------------
// Stage B body: GI = xbuf @ WIHT — ONE block computes all 3 gates for its
// 64-col slice (j = n0..n0+63 in [0,1024)), fused GRU gate epilogue.
// bx in [0,16), by in [0,4). Needs smem >= 4*64*40 ushorts.
// ---------------------------------------------------------------------------
__device__ __forceinline__ void stage_b_body(
    int t, int tt, int bx, int by, ushort* smem,
    const ushort* __restrict__ xbuf, const ushort* __restrict__ WIHT,
    const float* __restrict__ G, const float* __restrict__ bih,
    const float* __restrict__ bhh, const unsigned char* __restrict__ dones,
    float* __restrict__ H, ushort* __restrict__ HB, ushort* __restrict__ featc) {
  ushort* As  = smem;             // 64x40
  ushort* Bs0 = smem + 2560;
  ushort* Bs1 = smem + 2 * 2560;
  ushort* Bs2 = smem + 3 * 2560;
  int tid = threadIdx.x;
  int wave = tid >> 6, lane = tid & 63;
  int quad = lane >> 4, l15 = lane & 15;
  int m0 = by * 64, n0 = bx * 64;
  int sr = tid >> 2, sc = (tid & 3) * 8;
  const ushort* agp = xbuf + (size_t)(m0 + sr) * 288 + sc;
  const ushort* bgp0 = WIHT + (size_t)(n0 + sr) * 288 + sc;
  int4 pa = *(const int4*)agp;
  int4 pb0 = *(const int4*)bgp0;
  int4 pb1 = *(const int4*)(bgp0 + (size_t)1024 * 288);
  int4 pb2 = *(const int4*)(bgp0 + (size_t)2048 * 288);
  f32x4 accv[3][4] = {};
  for (int k0 = 0;;) {
    *(int4*)&As[sr * 40 + sc]  = pa;
    *(int4*)&Bs0[sr * 40 + sc] = pb0;
    *(int4*)&Bs1[sr * 40 + sc] = pb1;
    *(int4*)&Bs2[sr * 40 + sc] = pb2;
    __syncthreads();
    int kn = k0 + 32;
    if (kn < 288) {
      pa  = *(const int4*)(agp + kn);
      pb0 = *(const int4*)(bgp0 + kn);
      pb1 = *(const int4*)(bgp0 + (size_t)1024 * 288 + kn);
      pb2 = *(const int4*)(bgp0 + (size_t)2048 * 288 + kn);
    }
    short8 a = *(const short8*)&As[(wave * 16 + l15) * 40 + quad * 8];
#pragma unroll
    for (int c = 0; c < 4; ++c) {
      short8 b0v = *(const short8*)&Bs0[(c * 16 + l15) * 40 + quad * 8];
      accv[0][c] = __builtin_amdgcn_mfma_f32_16x16x32_bf16(a, b0v, accv[0][c], 0, 0, 0);
      short8 b1v = *(const short8*)&Bs1[(c * 16 + l15) * 40 + quad * 8];
      accv[1][c] = __builtin_amdgcn_mfma_f32_16x16x32_bf16(a, b1v, accv[1][c], 0, 0, 0);
      short8 b2v = *(const short8*)&Bs2[(c * 16 + l15) * 40 + quad * 8];
      accv[2][c] = __builtin_amdgcn_mfma_f32_16x16x32_bf16(a, b2v, accv[2][c], 0, 0, 0);
    }
    k0 = kn;
    if (k0 >= 288) break;
    __syncthreads();
  }
#pragma unroll
  for (int c = 0; c < 4; ++c) {
#pragma unroll
    for (int r = 0; r < 4; ++r) {
      int b_idx = m0 + wave * 16 + quad * 4 + r;
      int j = n0 + c * 16 + l15;
      const float* gp = G + (size_t)b_idx * 3072;
      float ir = accv[0][c][r] + bih[j];
      float iz = accv[1][c][r] + bih[1024 + j];
      float in_ = accv[2][c][r] + bih[2048 + j];
      float hr = gp[j] + bhh[j];
      float hz = gp[1024 + j] + bhh[1024 + j];
      float hn = gp[2048 + j] + bhh[2048 + j];
      float rg = 1.f / (1.f + expf(-(ir + hr)));
      float u = 1.f / (1.f + expf(-(iz + hz)));
      float n = tanhf(in_ + rg * hn);
      float hprev = H[b_idx * 1024 + j];
      float hnext = (1.f - u) * n + u * hprev;
      featc[(size_t)(tt * NB + b_idx) * 1280 + j] = f2bf(hnext);
      float mask = 1.f - (float)dones[t * NB + b_idx];
      float hm = hnext * mask;
      H[b_idx * 1024 + j] = hm;
      HB[b_idx * 1024 + j] = f2bf(hm);
    }
  }
}

// ---------------------------------------------------------------------------
// Cooperative Phase-B group kernel: 7 sequential steps, 2 grid syncs each.
// Grid 256 blocks x 256 threads (1 block/CU co-resident).
// ---------------------------------------------------------------------------
__global__ __launch_bounds__(256) void phase_b_group(
    int g, const ushort* __restrict__ WHT, const ushort* __restrict__ WIHT,
    const float* __restrict__ prior_b, const float* __restrict__ poste,
    const float* __restrict__ eps, const float* __restrict__ actions,
    const float* __restrict__ bih, const float* __restrict__ bhh,
    const unsigned char* __restrict__ dones,
    float* __restrict__ G, float* __restrict__ H, ushort* __restrict__ HB,
    ushort* __restrict__ xbuf, ushort* __restrict__ featc,
    float* __restrict__ acc_kl) {
  cg::grid_group gridg = cg::this_grid();
  __shared__ __align__(16) ushort smem[10240];  // 20 KB shared by both stages
  for (int tt = 0; tt < TGRP; ++tt) {
    int t = g * TGRP + tt;
    stage_a_body(t, tt, blockIdx.x & 63, blockIdx.x >> 6, smem,
                 HB, WHT, prior_b, poste, eps, actions, G, xbuf, featc, acc_kl);
    __threadfence();
    gridg.sync();
    if (blockIdx.x < 64) {
      stage_b_body(t, tt, blockIdx.x & 15, blockIdx.x >> 4, smem,
                   xbuf, WIHT, G, bih, bhh, dones, H, HB, featc);
    }
    __threadfence();
    gridg.sync();
  }
}

// Standalone fallback kernels (R5 structure, known-good mappings)
__global__ __launch_bounds__(256) void step_g_kernel(
    int t, int tt, const ushort* __restrict__ HB, const ushort* __restrict__ WHT,
    const float* __restrict__ prior_b, const float* __restrict__ poste,
    const float* __restrict__ eps, const float* __restrict__ actions,
    float* __restrict__ G, ushort* __restrict__ xbuf,
    ushort* __restrict__ featc, float* __restrict__ acc_kl) {
  __shared__ __align__(16) ushort smem[2 * 64 * 72];
  stage_a_body(t, tt, blockIdx.x, blockIdx.y, smem,
               HB, WHT, prior_b, poste, eps, actions, G, xbuf, featc, acc_kl);
}

__global__ __launch_bounds__(256) void gru_step_kernel(
    int t, int tt, const ushort* __restrict__ xbuf, const ushort* __restrict__ WIHT,
    const float* __restrict__ G, const float* __restrict__ bih,
    const float* __restrict__ bhh, const unsigned char* __restrict__ dones,
    float* __restrict__ H, ushort* __restrict__ HB, ushort* __restrict__ featc) {
  __shared__ __align__(16) ushort smem[4 * 64 * 40];
  stage_b_body(t, tt, blockIdx.x, blockIdx.y, smem,
               xbuf, WIHT, G, bih, bhh, dones, H, HB, featc);
}

// ---------------------------------------------------------------------------
// Decoder-out GEMM + fused recon loss. A = DR1C bf16 cols 0:1024 (lda 2048),
// BT = DW2T [512][1024]. M=1792, N=512, K=1024. grid (8, 28).
// ---------------------------------------------------------------------------
__global__ __launch_bounds__(256) void decobs_loss_kernel(
    const ushort* __restrict__ A, const ushort* __restrict__ BT,
    const float* __restrict__ bias, const float* __restrict__ obs_next_g,
    float* __restrict__ acc) {
  __shared__ __align__(16) ushort As[64 * 40];
  __shared__ __align__(16) ushort Bs[64 * 40];
  int tid = threadIdx.x;
  int wave = tid >> 6, lane = tid & 63;
  int quad = lane >> 4, l15 = lane & 15;
  int m0 = blockIdx.y * 64, n0 = blockIdx.x * 64;
  int sr = tid >> 2, sc = (tid & 3) * 8;
  f32x4 accm[4] = {};
  for (int k0 = 0; k0 < 1024; k0 += 32) {
    *(int4*)&As[sr * 40 + sc] = *(const int4*)(A + (size_t)(m0 + sr) * 2048 + k0 + sc);
    *(int4*)&Bs[sr * 40 + sc] = *(const int4*)(BT + (size_t)(n0 + sr) * 1024 + k0 + sc);
    __syncthreads();
    short8 a = *(const short8*)&As[(wave * 16 + l15) * 40 + quad * 8];
#pragma unroll
    for (int c = 0; c < 4; ++c) {
      short8 b = *(const short8*)&Bs[(c * 16 + l15) * 40 + quad * 8];
      accm[c] = __builtin_amdgcn_mfma_f32_16x16x32_bf16(a, b, accm[c], 0, 0, 0);
    }
    __syncthreads();
  }
  float local = 0.f;
#pragma unroll
  for (int c = 0; c < 4; ++c) {
#pragma unroll
    for (int r = 0; r < 4; ++r) {
      size_t row = m0 + wave * 16 + quad * 4 + r;
      int col = n0 + c * 16 + l15;
      float v = accm[c][r] + bias[col];
      float d = v - obs_next_g[row * 512 + col];
      local += d * d;
    }
  }
  __shared__ float red[256];
  red[tid] = local;
  __syncthreads();
  for (int st = 128; st > 0; st >>= 1) {
    if (tid < st) red[tid] += red[tid + st];
    __syncthreads();
  }
  if (tid == 0) atomicAdd(&acc[0], red[0]);
}

// Reward matvec + loss. R1 = DR1C + 1024 (bf16, row stride 2048).
__global__ __launch_bounds__(256) void rew_loss_kernel(
    const ushort* __restrict__ R1, const float* __restrict__ w2,
    const float* __restrict__ b2, const float* __restrict__ rewards_g,
    float* __restrict__ acc) {
  int wave = threadIdx.x >> 6;
  int lane = threadIdx.x & 63;
  int row = blockIdx.x * 4 + wave;
  const ushort* rp = R1 + (size_t)row * 2048;
  float s = 0.f;
#pragma unroll
  for (int i = 0; i < 16; ++i) s += bf2f(rp[lane + 64 * i]) * w2[lane + 64 * i];
  for (int off = 32; off > 0; off >>= 1) s += __shfl_down(s, off);
  if (lane == 0) {
    float d = s + b2[0] - rewards_g[row];
    atomicAdd(&acc[1], d * d);
  }
}

__global__ void finalize_kernel(const float* __restrict__ acc, float* __restrict__ out) {
  float recon = acc[0] / ((float)NROWS * 512.f);
  float rew = acc[1] / (float)NROWS;
  float kl = acc[2] / (float)NROWS;
  out[0] = recon + rew + kl;
  out[1] = recon;
  out[2] = rew;
  out[3] = kl;
}

}  // namespace

extern "C" void kernel_launch(void* const* d_in, const int* in_sizes, int n_in,
                              void* d_out, int out_size, void* d_ws, size_t ws_size,
                              hipStream_t stream) {
  const float* obs     = (const float*)d_in[0];
  const float* actions = (const float*)d_in[1];
  const float* rewards = (const float*)d_in[2];
  const unsigned char* dones = (const unsigned char*)d_in[3];
  const float* eps     = (const float*)d_in[4];
  const float* enc_w1  = (const float*)d_in[5];
  const float* enc_b1  = (const float*)d_in[6];
  const float* enc_w2  = (const float*)d_in[7];
  const float* enc_b2  = (const float*)d_in[8];
  const float* gru_wih = (const float*)d_in[9];
  const float* gru_whh = (const float*)d_in[10];
  const float* gru_bih = (const float*)d_in[11];
  const float* gru_bhh = (const float*)d_in[12];
  const float* prior_w = (const float*)d_in[13];
  const float* prior_b = (const float*)d_in[14];
  const float* post_w  = (const float*)d_in[15];
  const float* post_b  = (const float*)d_in[16];
  const float* dec_w1  = (const float*)d_in[17];
  const float* dec_b1  = (const float*)d_in[18];
  const float* dec_w2  = (const float*)d_in[19];
  const float* dec_b2  = (const float*)d_in[20];
  const float* rew_w1  = (const float*)d_in[21];
  const float* rew_b1  = (const float*)d_in[22];
  const float* rew_w2  = (const float*)d_in[23];
  const float* rew_b2  = (const float*)d_in[24];
  float* out = (float*)d_out;
  float* ws = (float*)d_ws;

  float*  POSTE = ws + OFF_POSTE;
  ushort* E1C   = (ushort*)(ws + OFF_E1C);
  ushort* EMBC  = (ushort*)(ws + OFF_EMBC);
  ushort* FEATC = (ushort*)(ws + OFF_FEATC);
  ushort* DR1C  = (ushort*)(ws + OFF_DR1C);
  ushort* WHT   = (ushort*)(ws + OFF_WHT);
  ushort* WIHT  = (ushort*)(ws + OFF_WIHT);
  ushort* WDRT  = (ushort*)(ws + OFF_WDRT);
  ushort* E1T   = (ushort*)(ws + OFF_E1T);
  ushort* E2T   = (ushort*)(ws + OFF_E2T);
  ushort* PET   = (ushort*)(ws + OFF_PET);
  ushort* DW2T  = (ushort*)(ws + OFF_DW2T);
  float*  BDR   = ws + OFF_BDR;
  float*  G     = ws + OFF_G;
  float*  H     = ws + OFF_H;
  ushort* HB    = (ushort*)(ws + OFF_HB);
  float*  ACC   = ws + OFF_ACC;
  ushort* XBUF  = (ushort*)(ws + OFF_XBUF);

  // Phase 0: zero H + HB + ACC (contiguous), build bf16 weights
  {
    int nzero = NB * 1024 + NB * 512 + 16;  // H + HB + ACC
    zero_kernel<<<(nzero + 255) / 256, 256, 0, stream>>>(H, nzero);
  }
  build_wht<<<4096 * 1024 / 256, 256, 0, stream>>>(prior_w, post_w, gru_whh, WHT);
  f2bf_kernel<<<(3072 * 288) / 256, 256, 0, stream>>>(gru_wih, WIHT, 3072 * 288);
  trans_conv<<<dim3(1024 / 32, 1280 / 32), 256, 0, stream>>>(dec_w1, WDRT, 1024, 1280);
  trans_conv<<<dim3(1024 / 32, 1280 / 32), 256, 0, stream>>>(rew_w1, WDRT + (size_t)1024 * 1280, 1024, 1280);
  trans_conv<<<dim3(1024 / 32, 512 / 32), 256, 0, stream>>>(enc_w1, E1T, 1024, 512);
  trans_conv<<<dim3(1024 / 32, 1024 / 32), 256, 0, stream>>>(enc_w2, E2T, 1024, 1024);
  trans_conv<<<dim3(512 / 32, 1024 / 32), 256, 0, stream>>>(post_w + (size_t)1024 * 512, PET, 512, 1024);
  trans_conv<<<dim3(512 / 32, 1024 / 32), 256, 0, stream>>>(dec_w2, DW2T, 512, 1024);
  build_bdr<<<8, 256, 0, stream>>>(dec_b1, rew_b1, BDR);

  // Phase A: encoder + posterior-from-emb, chunked per group
  for (int g = 0; g < NGRP; ++g) {
    const float* obs_g = obs + (size_t)g * GROWS * 512;
    gemm_obs<<<dim3(16, GROWS / 64), 256, 0, stream>>>(obs_g, E1T, enc_b1, E1C);
    gemm_bf16<1><<<dim3(16, GROWS / 64), 256, 0, stream>>>(
        E1C, E2T, enc_b2, EMBC, 1024, 1024, 1024, 1024);
    gemm_bf16<2><<<dim3(8, GROWS / 64), 256, 0, stream>>>(
        EMBC, PET, post_b, POSTE + (size_t)g * GROWS * 512, 1024, 1024, 1024, 512);
  }

  // Phase B: one cooperative launch per 7-step group (fallback: per-step
  // launches if cooperative launch is rejected), then per-group heads.
  for (int g = 0; g < NGRP; ++g) {
    int garg = g;
    float* acc_kl = &ACC[2];
    void* args[] = {&garg, &WHT, &WIHT, &prior_b, &POSTE, &eps, &actions,
                    &gru_bih, &gru_bhh, &dones, &G, &H, &HB, &XBUF, &FEATC, &acc_kl};
    hipError_t cerr = hipLaunchCooperativeKernel(
        (const void*)phase_b_group, dim3(256), dim3(256), args, 0, stream);
    if (cerr != hipSuccess) {
      for (int tt = 0; tt < TGRP; ++tt) {
        int t = g * TGRP + tt;
        step_g_kernel<<<dim3(64, 4), 256, 0, stream>>>(
            t, tt, HB, WHT, prior_b, POSTE, eps, actions, G, XBUF, FEATC, &ACC[2]);
        gru_step_kernel<<<dim3(16, 4), 256, 0, stream>>>(
            t, tt, XBUF, WIHT, G, gru_bih, gru_bhh, dones, H, HB, FEATC);
      }
    }
    gemm_bf16<1><<<dim3(32, GROWS / 64), 256, 0, stream>>>(
        FEATC, WDRT, BDR, DR1C, 1280, 1280, 1280, 2048);
    decobs_loss_kernel<<<dim3(8, GROWS / 64), 256, 0, stream>>>(
        DR1C, DW2T, dec_b2, obs + ((size_t)g * TGRP + 1) * NB * 512, ACC);
    rew_loss_kernel<<<GROWS / 4, 256, 0, stream>>>(
        DR1C + 1024, rew_w2, rew_b2, rewards + (size_t)g * TGRP * NB, ACC);
  }

  finalize_kernel<<<1, 1, 0, stream>>>(ACC, out);
}

// Round 8
// 4898.388 us; speedup vs baseline: 2.0043x; 2.0043x over previous
//
#include <hip/hip_runtime.h>
#include <math.h>

// ---------------------------------------------------------------------------
// WorldModel RSSM forward losses — R8.
// R7: cooperative cg::grid.sync() measured ~69us/sync -> phase_b_group 966us.
// R8: same persistent structure, custom lightweight grid barrier:
//   release-fence(agent) -> atomicAdd(agent) -> spin(s_sleep) -> acquire-fence.
// Monotonic counter in zeroed ws region; deterministic targets per launch.
// Fallback to per-step launches (R5 structure, 3135us) if coop launch fails.
// ---------------------------------------------------------------------------

namespace {

typedef unsigned short ushort;
typedef __attribute__((ext_vector_type(8))) short short8;   // 8 bf16 in 4 VGPRs
typedef __attribute__((ext_vector_type(4))) float f32x4;

constexpr int TSTEPS = 63;
constexpr int NB     = 256;
constexpr int NACT   = 32;
constexpr int NROWS  = TSTEPS * NB;   // 16128
constexpr int TGRP   = 7;
constexpr int NGRP   = 9;
constexpr int GROWS  = TGRP * NB;     // 1792 = 28*64

// ---- workspace layout (floats) --------------------------------------------
constexpr size_t OFF_POSTE = 0;                                     // f32 16128x512
constexpr size_t OFF_E1C   = OFF_POSTE + (size_t)NROWS * 512;       // u16 1792x1024
constexpr size_t OFF_EMBC  = OFF_E1C + (size_t)GROWS * 1024 / 2;    // u16 1792x1024
constexpr size_t OFF_FEATC = OFF_EMBC + (size_t)GROWS * 1024 / 2;   // u16 1792x1280
constexpr size_t OFF_DR1C  = OFF_FEATC + (size_t)GROWS * 1280 / 2;  // u16 1792x2048
constexpr size_t OFF_WHT   = OFF_DR1C + (size_t)GROWS * 2048 / 2;   // u16 4096x1024
constexpr size_t OFF_WIHT  = OFF_WHT + (size_t)4096 * 1024 / 2;     // u16 3072x288
constexpr size_t OFF_WDRT  = OFF_WIHT + (size_t)3072 * 288 / 2;     // u16 2048x1280
constexpr size_t OFF_E1T   = OFF_WDRT + (size_t)2048 * 1280 / 2;    // u16 1024x512
constexpr size_t OFF_E2T   = OFF_E1T + (size_t)1024 * 512 / 2;      // u16 1024x1024
constexpr size_t OFF_PET   = OFF_E2T + (size_t)1024 * 1024 / 2;     // u16 512x1024
constexpr size_t OFF_DW2T  = OFF_PET + (size_t)512 * 1024 / 2;      // u16 512x1024
constexpr size_t OFF_BDR   = OFF_DW2T + (size_t)512 * 1024 / 2;     // f32 2048
constexpr size_t OFF_G     = OFF_BDR + 2048;                        // f32 256x3072
constexpr size_t OFF_H     = OFF_G + (size_t)NB * 3072;             // f32 256x1024
constexpr size_t OFF_HB    = OFF_H + (size_t)NB * 1024;             // u16 256x1024
constexpr size_t OFF_ACC   = OFF_HB + (size_t)NB * 1024 / 2;        // f32 16 (bar at +8)
constexpr size_t OFF_XBUF  = OFF_ACC + 16;                          // u16 256x288

__device__ __forceinline__ ushort f2bf(float f) {
  unsigned int u = __float_as_uint(f);
  unsigned int r = (u + 0x7fffu + ((u >> 16) & 1u)) >> 16;
  return (ushort)r;
}
__device__ __forceinline__ float bf2f(ushort u) {
  return __uint_as_float((unsigned int)u << 16);
}

// Custom grid barrier: monotonic counter, agent-scope fences.
__device__ __forceinline__ void grid_barrier(unsigned* bar, unsigned target) {
  __syncthreads();
  if (threadIdx.x == 0) {
    __builtin_amdgcn_fence(__ATOMIC_RELEASE, "agent");
    __hip_atomic_fetch_add(bar, 1u, __ATOMIC_RELAXED, __HIP_MEMORY_SCOPE_AGENT);
    while (__hip_atomic_load(bar, __ATOMIC_RELAXED, __HIP_MEMORY_SCOPE_AGENT) < target)
      __builtin_amdgcn_s_sleep(1);
    __builtin_amdgcn_fence(__ATOMIC_ACQUIRE, "agent");
  }
  __syncthreads();
}

__global__ void zero_kernel(float* p, int n) {
  int i = blockIdx.x * 256 + threadIdx.x;
  if (i < n) p[i] = 0.f;
}

__global__ void f2bf_kernel(const float* __restrict__ in, ushort* __restrict__ out, int n) {
  int i = blockIdx.x * 256 + threadIdx.x;
  if (i < n) out[i] = f2bf(in[i]);
}

// WHT[n][k]. n<1024: latent-permuted — quad q=(n>>4)&3 selects pm/pl/qm/ql,
// s = (n>>6)*16 + (n&15). n>=1024: whh[n-1024][k].
__global__ void build_wht(const float* __restrict__ prior_w, const float* __restrict__ post_w,
                          const float* __restrict__ whh, ushort* __restrict__ out) {
  int idx = blockIdx.x * 256 + threadIdx.x;  // 4096*1024
  int n = idx >> 10, k = idx & 1023;
  float v;
  if (n < 1024) {
    int q = (n >> 4) & 3;
    int s = ((n >> 6) << 4) | (n & 15);
    v = (q == 0) ? prior_w[k * 512 + s]
      : (q == 1) ? prior_w[k * 512 + 256 + s]
      : (q == 2) ? post_w[k * 512 + s]
                 : post_w[k * 512 + 256 + s];
  } else {
    v = whh[(size_t)(n - 1024) * 1024 + k];
  }
  out[idx] = f2bf(v);
}

// out[c*ldo + r] = bf16(in[r*ldi + c]); grid (C/32, R/32)
__global__ void trans_conv(const float* __restrict__ in, ushort* __restrict__ out,
                           int ldi, int ldo) {
  __shared__ float tile[32][33];
  int r0 = blockIdx.y * 32, c0 = blockIdx.x * 32;
  int tx = threadIdx.x & 31, ty = threadIdx.x >> 5;
#pragma unroll
  for (int p = 0; p < 4; ++p)
    tile[ty + p * 8][tx] = in[(size_t)(r0 + ty + p * 8) * ldi + c0 + tx];
  __syncthreads();
#pragma unroll
  for (int p = 0; p < 4; ++p)
    out[(size_t)(c0 + ty + p * 8) * ldo + r0 + tx] = f2bf(tile[tx][ty + p * 8]);
}

__global__ void build_bdr(const float* __restrict__ dec_b1, const float* __restrict__ rew_b1,
                          float* __restrict__ bdr) {
  int i = blockIdx.x * 256 + threadIdx.x;  // 2048
  bdr[i] = (i < 1024) ? dec_b1[i] : rew_b1[i - 1024];
}

// ---------------------------------------------------------------------------
// Phase A/C bf16 GEMM: C[M,N] = A @ B; A bf16 [M][K], BT bf16 [N][K].
// 64x64 tile, 4 waves, BK=32, LDS stride 40.
// EPI: 1 = +bias, relu, store bf16; 2 = +bias, store f32.
// ---------------------------------------------------------------------------
template <int EPI>
__global__ __launch_bounds__(256) void gemm_bf16(
    const ushort* __restrict__ A, const ushort* __restrict__ BT,
    const float* __restrict__ bias, void* __restrict__ Cv,
    int K, int lda, int ldb, int ldc) {
  __shared__ __align__(16) ushort As[64 * 40];
  __shared__ __align__(16) ushort Bs[64 * 40];
  int tid = threadIdx.x;
  int wave = tid >> 6, lane = tid & 63;
  int quad = lane >> 4, l15 = lane & 15;
  int m0 = blockIdx.y * 64, n0 = blockIdx.x * 64;
  int sr = tid >> 2, sc = (tid & 3) * 8;
  f32x4 acc[4] = {};
  for (int k0 = 0; k0 < K; k0 += 32) {
    *(int4*)&As[sr * 40 + sc] = *(const int4*)(A + (size_t)(m0 + sr) * lda + k0 + sc);
    *(int4*)&Bs[sr * 40 + sc] = *(const int4*)(BT + (size_t)(n0 + sr) * ldb + k0 + sc);
    __syncthreads();
    short8 a = *(const short8*)&As[(wave * 16 + l15) * 40 + quad * 8];
#pragma unroll
    for (int c = 0; c < 4; ++c) {
      short8 b = *(const short8*)&Bs[(c * 16 + l15) * 40 + quad * 8];
      acc[c] = __builtin_amdgcn_mfma_f32_16x16x32_bf16(a, b, acc[c], 0, 0, 0);
    }
    __syncthreads();
  }
#pragma unroll
  for (int c = 0; c < 4; ++c) {
#pragma unroll
    for (int r = 0; r < 4; ++r) {
      size_t row = m0 + wave * 16 + quad * 4 + r;
      int col = n0 + c * 16 + l15;
      float v = acc[c][r] + bias[col];
      if (EPI == 1) v = fmaxf(v, 0.f);
      if (EPI == 1) ((ushort*)Cv)[row * ldc + col] = f2bf(v);
      else ((float*)Cv)[row * ldc + col] = v;
    }
  }
}

// Encoder layer 1 with fused f32->bf16 A staging. A = obs f32 [M][512],
// BT = E1T [1024][512]. M=1792, N=1024, K=512. grid (16, 28). relu, bf16 out.
__global__ __launch_bounds__(256) void gemm_obs(
    const float* __restrict__ A, const ushort* __restrict__ BT,
    const float* __restrict__ bias, ushort* __restrict__ C) {
  __shared__ __align__(16) ushort As[64 * 40];
  __shared__ __align__(16) ushort Bs[64 * 40];
  int tid = threadIdx.x;
  int wave = tid >> 6, lane = tid & 63;
  int quad = lane >> 4, l15 = lane & 15;
  int m0 = blockIdx.y * 64, n0 = blockIdx.x * 64;
  int sr = tid >> 2, sc = (tid & 3) * 8;
  f32x4 acc[4] = {};
  for (int k0 = 0; k0 < 512; k0 += 32) {
    float4 f0 = *(const float4*)(A + (size_t)(m0 + sr) * 512 + k0 + sc);
    float4 f1 = *(const float4*)(A + (size_t)(m0 + sr) * 512 + k0 + sc + 4);
    union { int4 v; ushort u[8]; } cvt;
    cvt.u[0] = f2bf(f0.x); cvt.u[1] = f2bf(f0.y); cvt.u[2] = f2bf(f0.z); cvt.u[3] = f2bf(f0.w);
    cvt.u[4] = f2bf(f1.x); cvt.u[5] = f2bf(f1.y); cvt.u[6] = f2bf(f1.z); cvt.u[7] = f2bf(f1.w);
    *(int4*)&As[sr * 40 + sc] = cvt.v;
    *(int4*)&Bs[sr * 40 + sc] = *(const int4*)(BT + (size_t)(n0 + sr) * 512 + k0 + sc);
    __syncthreads();
    short8 a = *(const short8*)&As[(wave * 16 + l15) * 40 + quad * 8];
#pragma unroll
    for (int c = 0; c < 4; ++c) {
      short8 b = *(const short8*)&Bs[(c * 16 + l15) * 40 + quad * 8];
      acc[c] = __builtin_amdgcn_mfma_f32_16x16x32_bf16(a, b, acc[c], 0, 0, 0);
    }
    __syncthreads();
  }
#pragma unroll
  for (int c = 0; c < 4; ++c) {
#pragma unroll
    for (int r = 0; r < 4; ++r) {
      size_t row = m0 + wave * 16 + quad * 4 + r;
      int col = n0 + c * 16 + l15;
      float v = fmaxf(acc[c][r] + bias[col], 0.f);
      C[row * 1024 + col] = f2bf(v);
    }
  }
}

// ---------------------------------------------------------------------------
// Stage A body: one 64x64 tile of G = HB @ WHT (M=256,N=4096,K=1024), BK=64,
// register prefetch. bx<16 -> latent-permuted cols, fused z/KL epilogue;
// else store gh to G [256][3072] f32. by in [0,4). smem >= 2*64*72 ushorts.
// ---------------------------------------------------------------------------
__device__ __forceinline__ void stage_a_body(
    int t, int tt, int bx, int by, ushort* smem,
    const ushort* __restrict__ HB, const ushort* __restrict__ WHT,
    const float* __restrict__ prior_b, const float* __restrict__ poste,
    const float* __restrict__ eps, const float* __restrict__ actions,
    float* __restrict__ G, ushort* __restrict__ xbuf,
    ushort* __restrict__ featc, float* __restrict__ acc_kl) {
  ushort* As = smem;            // 64x72
  ushort* Bs = smem + 64 * 72;  // 64x72
  int tid = threadIdx.x;
  int wave = tid >> 6, lane = tid & 63;
  int quad = lane >> 4, l15 = lane & 15;
  int m0 = by * 64, n0 = bx * 64;
  int sr = tid >> 2, sc = (tid & 3) * 16;
  const ushort* agp = HB + (size_t)(m0 + sr) * 1024 + sc;
  const ushort* bgp = WHT + (size_t)(n0 + sr) * 1024 + sc;
  int4 a0 = *(const int4*)agp, a1 = *(const int4*)(agp + 8);
  int4 b0 = *(const int4*)bgp, b1 = *(const int4*)(bgp + 8);
  f32x4 acc[4] = {};
  for (int k0 = 0;;) {
    *(int4*)&As[sr * 72 + sc] = a0; *(int4*)&As[sr * 72 + sc + 8] = a1;
    *(int4*)&Bs[sr * 72 + sc] = b0; *(int4*)&Bs[sr * 72 + sc + 8] = b1;
    __syncthreads();
    int kn = k0 + 64;
    if (kn < 1024) {
      a0 = *(const int4*)(agp + kn); a1 = *(const int4*)(agp + kn + 8);
      b0 = *(const int4*)(bgp + kn); b1 = *(const int4*)(bgp + kn + 8);
    }
#pragma unroll
    for (int kk = 0; kk < 2; ++kk) {
      short8 a = *(const short8*)&As[(wave * 16 + l15) * 72 + kk * 32 + quad * 8];
#pragma unroll
      for (int c = 0; c < 4; ++c) {
        short8 b = *(const short8*)&Bs[(c * 16 + l15) * 72 + kk * 32 + quad * 8];
        acc[c] = __builtin_amdgcn_mfma_f32_16x16x32_bf16(a, b, acc[c], 0, 0, 0);
      }
    }
    k0 = kn;
    if (k0 >= 1024) break;
    __syncthreads();
  }
  if (bx < 16) {
    int s = (n0 >> 2) + l15;
    float kl_sum = 0.f;
#pragma unroll
    for (int r = 0; r < 4; ++r) {
      int b = m0 + wave * 16 + quad * 4 + r;
      size_t row = (size_t)t * NB + b;
      float pm = acc[0][r] + prior_b[s];
      float pl = acc[1][r] + prior_b[256 + s];
      float qm = acc[2][r] + poste[row * 512 + s];
      float ql = acc[3][r] + poste[row * 512 + 256 + s];
      float e = eps[row * 256 + s];
      float z = qm + e * expf(ql);
      xbuf[b * 288 + s] = f2bf(z);
      featc[(size_t)(tt * NB + b) * 1280 + 1024 + s] = f2bf(z);
      if (s < NACT) xbuf[b * 288 + 256 + s] = f2bf(actions[row * NACT + s]);
      float vq = expf(2.f * ql), vp = expf(2.f * pl);
      float dm = qm - pm;
      kl_sum += pl - ql + (vq + dm * dm) / (vp + 1e-8f) - 1.f;
    }
    for (int off = 32; off > 0; off >>= 1) kl_sum += __shfl_down(kl_sum, off);
    if (lane == 0) atomicAdd(acc_kl, 0.5f * kl_sum);
  } else {
    int ng = n0 - 1024;
#pragma unroll
    for (int c = 0; c < 4; ++c)
#pragma unroll
      for (int r = 0; r < 4; ++r) {
        int b = m0 + wave * 16 + quad * 4 + r;
        G[(size_t)b * 3072 + ng + c * 16 + l15] = acc[c][r];
      }
  }
}

// ---------------------------------------------------------------------------
// Stage B body: GI = xbuf @ WIHT — one block computes all 3 gates for its
// 64-col slice (j in [0,1024)), fused GRU gate epilogue. bx in [0,16),
// by in [0,4). smem >= 4*64*40 ushorts.
// ---------------------------------------------------------------------------
__device__ __forceinline__ void stage_b_body(
    int t, int tt, int bx, int by, ushort* smem,
    const ushort* __restrict__ xbuf, const ushort* __restrict__ WIHT,
    const float* __restrict__ G, const float* __restrict__ bih,
    const float* __restrict__ bhh, const unsigned char* __restrict__ dones,
    float* __restrict__ H, ushort* __restrict__ HB, ushort* __restrict__ featc) {
  ushort* As  = smem;             // 64x40
  ushort* Bs0 = smem + 2560;
  ushort* Bs1 = smem + 2 * 2560;
  ushort* Bs2 = smem + 3 * 2560;
  int tid = threadIdx.x;
  int wave = tid >> 6, lane = tid & 63;
  int quad = lane >> 4, l15 = lane & 15;
  int m0 = by * 64, n0 = bx * 64;
  int sr = tid >> 2, sc = (tid & 3) * 8;
  const ushort* agp = xbuf + (size_t)(m0 + sr) * 288 + sc;
  const ushort* bgp0 = WIHT + (size_t)(n0 + sr) * 288 + sc;
  int4 pa = *(const int4*)agp;
  int4 pb0 = *(const int4*)bgp0;
  int4 pb1 = *(const int4*)(bgp0 + (size_t)1024 * 288);
  int4 pb2 = *(const int4*)(bgp0 + (size_t)2048 * 288);
  f32x4 accv[3][4] = {};
  for (int k0 = 0;;) {
    *(int4*)&As[sr * 40 + sc]  = pa;
    *(int4*)&Bs0[sr * 40 + sc] = pb0;
    *(int4*)&Bs1[sr * 40 + sc] = pb1;
    *(int4*)&Bs2[sr * 40 + sc] = pb2;
    __syncthreads();
    int kn = k0 + 32;
    if (kn < 288) {
      pa  = *(const int4*)(agp + kn);
      pb0 = *(const int4*)(bgp0 + kn);
      pb1 = *(const int4*)(bgp0 + (size_t)1024 * 288 + kn);
      pb2 = *(const int4*)(bgp0 + (size_t)2048 * 288 + kn);
    }
    short8 a = *(const short8*)&As[(wave * 16 + l15) * 40 + quad * 8];
#pragma unroll
    for (int c = 0; c < 4; ++c) {
      short8 b0v = *(const short8*)&Bs0[(c * 16 + l15) * 40 + quad * 8];
      accv[0][c] = __builtin_amdgcn_mfma_f32_16x16x32_bf16(a, b0v, accv[0][c], 0, 0, 0);
      short8 b1v = *(const short8*)&Bs1[(c * 16 + l15) * 40 + quad * 8];
      accv[1][c] = __builtin_amdgcn_mfma_f32_16x16x32_bf16(a, b1v, accv[1][c], 0, 0, 0);
      short8 b2v = *(const short8*)&Bs2[(c * 16 + l15) * 40 + quad * 8];
      accv[2][c] = __builtin_amdgcn_mfma_f32_16x16x32_bf16(a, b2v, accv[2][c], 0, 0, 0);
    }
    k0 = kn;
    if (k0 >= 288) break;
    __syncthreads();
  }
#pragma unroll
  for (int c = 0; c < 4; ++c) {
#pragma unroll
    for (int r = 0; r < 4; ++r) {
      int b_idx = m0 + wave * 16 + quad * 4 + r;
      int j = n0 + c * 16 + l15;
      const float* gp = G + (size_t)b_idx * 3072;
      float ir = accv[0][c][r] + bih[j];
      float iz = accv[1][c][r] + bih[1024 + j];
      float in_ = accv[2][c][r] + bih[2048 + j];
      float hr = gp[j] + bhh[j];
      float hz = gp[1024 + j] + bhh[1024 + j];
      float hn = gp[2048 + j] + bhh[2048 + j];
      float rg = 1.f / (1.f + expf(-(ir + hr)));
      float u = 1.f / (1.f + expf(-(iz + hz)));
      float n = tanhf(in_ + rg * hn);
      float hprev = H[b_idx * 1024 + j];
      float hnext = (1.f - u) * n + u * hprev;
      featc[(size_t)(tt * NB + b_idx) * 1280 + j] = f2bf(hnext);
      float mask = 1.f - (float)dones[t * NB + b_idx];
      float hm = hnext * mask;
      H[b_idx * 1024 + j] = hm;
      HB[b_idx * 1024 + j] = f2bf(hm);
    }
  }
}

// ---------------------------------------------------------------------------
// Persistent Phase-B group kernel with custom barriers. Grid 256x256.
// 13 barriers per launch (last step's trailing barrier elided — kernel end).
// ---------------------------------------------------------------------------
__global__ __launch_bounds__(256) void phase_b_group(
    int g, const ushort* __restrict__ WHT, const ushort* __restrict__ WIHT,
    const float* __restrict__ prior_b, const float* __restrict__ poste,
    const float* __restrict__ eps, const float* __restrict__ actions,
    const float* __restrict__ bih, const float* __restrict__ bhh,
    const unsigned char* __restrict__ dones,
    float* __restrict__ G, float* __restrict__ H, ushort* __restrict__ HB,
    ushort* __restrict__ xbuf, ushort* __restrict__ featc,
    float* __restrict__ acc_kl, unsigned* __restrict__ bar) {
  __shared__ __align__(16) ushort smem[10240];  // 20 KB shared by both stages
  unsigned barix = (unsigned)g * 13u;
  for (int tt = 0; tt < TGRP; ++tt) {
    int t = g * TGRP + tt;
    stage_a_body(t, tt, blockIdx.x & 63, blockIdx.x >> 6, smem,
                 HB, WHT, prior_b, poste, eps, actions, G, xbuf, featc, acc_kl);
    grid_barrier(bar, 256u * (++barix));
    if (blockIdx.x < 64) {
      stage_b_body(t, tt, blockIdx.x & 15, blockIdx.x >> 4, smem,
                   xbuf, WIHT, G, bih, bhh, dones, H, HB, featc);
    }
    if (tt + 1 < TGRP) grid_barrier(bar, 256u * (++barix));
  }
}

// Standalone fallback kernels (R5 structure, known-good)
__global__ __launch_bounds__(256) void step_g_kernel(
    int t, int tt, const ushort* __restrict__ HB, const ushort* __restrict__ WHT,
    const float* __restrict__ prior_b, const float* __restrict__ poste,
    const float* __restrict__ eps, const float* __restrict__ actions,
    float* __restrict__ G, ushort* __restrict__ xbuf,
    ushort* __restrict__ featc, float* __restrict__ acc_kl) {
  __shared__ __align__(16) ushort smem[2 * 64 * 72];
  stage_a_body(t, tt, blockIdx.x, blockIdx.y, smem,
               HB, WHT, prior_b, poste, eps, actions, G, xbuf, featc, acc_kl);
}

__global__ __launch_bounds__(256) void gru_step_kernel(
    int t, int tt, const ushort* __restrict__ xbuf, const ushort* __restrict__ WIHT,
    const float* __restrict__ G, const float* __restrict__ bih,
    const float* __restrict__ bhh, const unsigned char* __restrict__ dones,
    float* __restrict__ H, ushort* __restrict__ HB, ushort* __restrict__ featc) {
  __shared__ __align__(16) ushort smem[4 * 64 * 40];
  stage_b_body(t, tt, blockIdx.x, blockIdx.y, smem,
               xbuf, WIHT, G, bih, bhh, dones, H, HB, featc);
}

// ---------------------------------------------------------------------------
// Decoder-out GEMM + fused recon loss. A = DR1C bf16 cols 0:1024 (lda 2048),
// BT = DW2T [512][1024]. M=1792, N=512, K=1024. grid (8, 28).
// ---------------------------------------------------------------------------
__global__ __launch_bounds__(256) void decobs_loss_kernel(
    const ushort* __restrict__ A, const ushort* __restrict__ BT,
    const float* __restrict__ bias, const float* __restrict__ obs_next_g,
    float* __restrict__ acc) {
  __shared__ __align__(16) ushort As[64 * 40];
  __shared__ __align__(16) ushort Bs[64 * 40];
  int tid = threadIdx.x;
  int wave = tid >> 6, lane = tid & 63;
  int quad = lane >> 4, l15 = lane & 15;
  int m0 = blockIdx.y * 64, n0 = blockIdx.x * 64;
  int sr = tid >> 2, sc = (tid & 3) * 8;
  f32x4 accm[4] = {};
  for (int k0 = 0; k0 < 1024; k0 += 32) {
    *(int4*)&As[sr * 40 + sc] = *(const int4*)(A + (size_t)(m0 + sr) * 2048 + k0 + sc);
    *(int4*)&Bs[sr * 40 + sc] = *(const int4*)(BT + (size_t)(n0 + sr) * 1024 + k0 + sc);
    __syncthreads();
    short8 a = *(const short8*)&As[(wave * 16 + l15) * 40 + quad * 8];
#pragma unroll
    for (int c = 0; c < 4; ++c) {
      short8 b = *(const short8*)&Bs[(c * 16 + l15) * 40 + quad * 8];
      accm[c] = __builtin_amdgcn_mfma_f32_16x16x32_bf16(a, b, accm[c], 0, 0, 0);
    }
    __syncthreads();
  }
  float local = 0.f;
#pragma unroll
  for (int c = 0; c < 4; ++c) {
#pragma unroll
    for (int r = 0; r < 4; ++r) {
      size_t row = m0 + wave * 16 + quad * 4 + r;
      int col = n0 + c * 16 + l15;
      float v = accm[c][r] + bias[col];
      float d = v - obs_next_g[row * 512 + col];
      local += d * d;
    }
  }
  __shared__ float red[256];
  red[tid] = local;
  __syncthreads();
  for (int st = 128; st > 0; st >>= 1) {
    if (tid < st) red[tid] += red[tid + st];
    __syncthreads();
  }
  if (tid == 0) atomicAdd(&acc[0], red[0]);
}

// Reward matvec + loss. R1 = DR1C + 1024 (bf16, row stride 2048).
__global__ __launch_bounds__(256) void rew_loss_kernel(
    const ushort* __restrict__ R1, const float* __restrict__ w2,
    const float* __restrict__ b2, const float* __restrict__ rewards_g,
    float* __restrict__ acc) {
  int wave = threadIdx.x >> 6;
  int lane = threadIdx.x & 63;
  int row = blockIdx.x * 4 + wave;
  const ushort* rp = R1 + (size_t)row * 2048;
  float s = 0.f;
#pragma unroll
  for (int i = 0; i < 16; ++i) s += bf2f(rp[lane + 64 * i]) * w2[lane + 64 * i];
  for (int off = 32; off > 0; off >>= 1) s += __shfl_down(s, off);
  if (lane == 0) {
    float d = s + b2[0] - rewards_g[row];
    atomicAdd(&acc[1], d * d);
  }
}

__global__ void finalize_kernel(const float* __restrict__ acc, float* __restrict__ out) {
  float recon = acc[0] / ((float)NROWS * 512.f);
  float rew = acc[1] / (float)NROWS;
  float kl = acc[2] / (float)NROWS;
  out[0] = recon + rew + kl;
  out[1] = recon;
  out[2] = rew;
  out[3] = kl;
}

}  // namespace

extern "C" void kernel_launch(void* const* d_in, const int* in_sizes, int n_in,
                              void* d_out, int out_size, void* d_ws, size_t ws_size,
                              hipStream_t stream) {
  const float* obs     = (const float*)d_in[0];
  const float* actions = (const float*)d_in[1];
  const float* rewards = (const float*)d_in[2];
  const unsigned char* dones = (const unsigned char*)d_in[3];
  const float* eps     = (const float*)d_in[4];
  const float* enc_w1  = (const float*)d_in[5];
  const float* enc_b1  = (const float*)d_in[6];
  const float* enc_w2  = (const float*)d_in[7];
  const float* enc_b2  = (const float*)d_in[8];
  const float* gru_wih = (const float*)d_in[9];
  const float* gru_whh = (const float*)d_in[10];
  const float* gru_bih = (const float*)d_in[11];
  const float* gru_bhh = (const float*)d_in[12];
  const float* prior_w = (const float*)d_in[13];
  const float* prior_b = (const float*)d_in[14];
  const float* post_w  = (const float*)d_in[15];
  const float* post_b  = (const float*)d_in[16];
  const float* dec_w1  = (const float*)d_in[17];
  const float* dec_b1  = (const float*)d_in[18];
  const float* dec_w2  = (const float*)d_in[19];
  const float* dec_b2  = (const float*)d_in[20];
  const float* rew_w1  = (const float*)d_in[21];
  const float* rew_b1  = (const float*)d_in[22];
  const float* rew_w2  = (const float*)d_in[23];
  const float* rew_b2  = (const float*)d_in[24];
  float* out = (float*)d_out;
  float* ws = (float*)d_ws;

  float*  POSTE = ws + OFF_POSTE;
  ushort* E1C   = (ushort*)(ws + OFF_E1C);
  ushort* EMBC  = (ushort*)(ws + OFF_EMBC);
  ushort* FEATC = (ushort*)(ws + OFF_FEATC);
  ushort* DR1C  = (ushort*)(ws + OFF_DR1C);
  ushort* WHT   = (ushort*)(ws + OFF_WHT);
  ushort* WIHT  = (ushort*)(ws + OFF_WIHT);
  ushort* WDRT  = (ushort*)(ws + OFF_WDRT);
  ushort* E1T   = (ushort*)(ws + OFF_E1T);
  ushort* E2T   = (ushort*)(ws + OFF_E2T);
  ushort* PET   = (ushort*)(ws + OFF_PET);
  ushort* DW2T  = (ushort*)(ws + OFF_DW2T);
  float*  BDR   = ws + OFF_BDR;
  float*  G     = ws + OFF_G;
  float*  H     = ws + OFF_H;
  ushort* HB    = (ushort*)(ws + OFF_HB);
  float*  ACC   = ws + OFF_ACC;
  unsigned* BAR = (unsigned*)(ws + OFF_ACC + 8);
  ushort* XBUF  = (ushort*)(ws + OFF_XBUF);

  // Phase 0: zero H + HB + ACC(incl. barrier counter), build bf16 weights
  {
    int nzero = NB * 1024 + NB * 512 + 16;  // H + HB + ACC
    zero_kernel<<<(nzero + 255) / 256, 256, 0, stream>>>(H, nzero);
  }
  build_wht<<<4096 * 1024 / 256, 256, 0, stream>>>(prior_w, post_w, gru_whh, WHT);
  f2bf_kernel<<<(3072 * 288) / 256, 256, 0, stream>>>(gru_wih, WIHT, 3072 * 288);
  trans_conv<<<dim3(1024 / 32, 1280 / 32), 256, 0, stream>>>(dec_w1, WDRT, 1024, 1280);
  trans_conv<<<dim3(1024 / 32, 1280 / 32), 256, 0, stream>>>(rew_w1, WDRT + (size_t)1024 * 1280, 1024, 1280);
  trans_conv<<<dim3(1024 / 32, 512 / 32), 256, 0, stream>>>(enc_w1, E1T, 1024, 512);
  trans_conv<<<dim3(1024 / 32, 1024 / 32), 256, 0, stream>>>(enc_w2, E2T, 1024, 1024);
  trans_conv<<<dim3(512 / 32, 1024 / 32), 256, 0, stream>>>(post_w + (size_t)1024 * 512, PET, 512, 1024);
  trans_conv<<<dim3(512 / 32, 1024 / 32), 256, 0, stream>>>(dec_w2, DW2T, 512, 1024);
  build_bdr<<<8, 256, 0, stream>>>(dec_b1, rew_b1, BDR);

  // Phase A: encoder + posterior-from-emb, chunked per group
  for (int g = 0; g < NGRP; ++g) {
    const float* obs_g = obs + (size_t)g * GROWS * 512;
    gemm_obs<<<dim3(16, GROWS / 64), 256, 0, stream>>>(obs_g, E1T, enc_b1, E1C);
    gemm_bf16<1><<<dim3(16, GROWS / 64), 256, 0, stream>>>(
        E1C, E2T, enc_b2, EMBC, 1024, 1024, 1024, 1024);
    gemm_bf16<2><<<dim3(8, GROWS / 64), 256, 0, stream>>>(
        EMBC, PET, post_b, POSTE + (size_t)g * GROWS * 512, 1024, 1024, 1024, 512);
  }

  // Phase B: persistent kernel with custom barrier per group (fallback:
  // per-step launches), then per-group heads.
  for (int g = 0; g < NGRP; ++g) {
    int garg = g;
    float* acc_kl = &ACC[2];
    unsigned* barp = BAR;
    void* args[] = {&garg, &WHT, &WIHT, &prior_b, &POSTE, &eps, &actions,
                    &gru_bih, &gru_bhh, &dones, &G, &H, &HB, &XBUF, &FEATC,
                    &acc_kl, &barp};
    hipError_t cerr = hipLaunchCooperativeKernel(
        (const void*)phase_b_group, dim3(256), dim3(256), args, 0, stream);
    if (cerr != hipSuccess) {
      for (int tt = 0; tt < TGRP; ++tt) {
        int t = g * TGRP + tt;
        step_g_kernel<<<dim3(64, 4), 256, 0, stream>>>(
            t, tt, HB, WHT, prior_b, POSTE, eps, actions, G, XBUF, FEATC, &ACC[2]);
        gru_step_kernel<<<dim3(16, 4), 256, 0, stream>>>(
            t, tt, XBUF, WIHT, G, gru_bih, gru_bhh, dones, H, HB, FEATC);
      }
    }
    gemm_bf16<1><<<dim3(32, GROWS / 64), 256, 0, stream>>>(
        FEATC, WDRT, BDR, DR1C, 1280, 1280, 1280, 2048);
    decobs_loss_kernel<<<dim3(8, GROWS / 64), 256, 0, stream>>>(
        DR1C, DW2T, dec_b2, obs + ((size_t)g * TGRP + 1) * NB * 512, ACC);
    rew_loss_kernel<<<GROWS / 4, 256, 0, stream>>>(
        DR1C + 1024, rew_w2, rew_b2, rewards + (size_t)g * TGRP * NB, ACC);
  }

  finalize_kernel<<<1, 1, 0, stream>>>(ACC, out);
}

// Round 9
// 4594.943 us; speedup vs baseline: 2.1366x; 1.0660x over previous
//
#include <hip/hip_runtime.h>
#include <math.h>

// ---------------------------------------------------------------------------
// WorldModel RSSM forward losses — R9.
// R8: custom single-counter barrier = ~30us (256 serialized RMW on one IC
// line). R9: contention-free slot barrier (per-block monotonic stores, each
// thread polls one slot), ONE persistent Phase-B launch for all 63 steps,
// Phase A/C unchunked full-size (DR1 aliases E1+EMB; 166MB < 256MiB ws),
// KL block-reduced to 1 atomic/block.
// ---------------------------------------------------------------------------

namespace {

typedef unsigned short ushort;
typedef __attribute__((ext_vector_type(8))) short short8;   // 8 bf16 in 4 VGPRs
typedef __attribute__((ext_vector_type(4))) float f32x4;

constexpr int TSTEPS = 63;
constexpr int NB     = 256;
constexpr int NACT   = 32;
constexpr int NROWS  = TSTEPS * NB;   // 16128

// ---- workspace layout (floats), total ~41.5M floats = 166 MB --------------
constexpr size_t OFF_POSTE = 0;                                   // f32 16128x512
constexpr size_t OFF_E1    = OFF_POSTE + (size_t)NROWS * 512;     // u16 16128x1024
constexpr size_t OFF_EMB   = OFF_E1 + (size_t)NROWS * 1024 / 2;   // u16 16128x1024
constexpr size_t OFF_DR1   = OFF_E1;                              // u16 16128x2048 (alias E1+EMB)
constexpr size_t OFF_FEAT  = OFF_EMB + (size_t)NROWS * 1024 / 2;  // u16 16128x1280
constexpr size_t OFF_WHT   = OFF_FEAT + (size_t)NROWS * 1280 / 2; // u16 4096x1024
constexpr size_t OFF_WIHT  = OFF_WHT + (size_t)4096 * 1024 / 2;   // u16 3072x288
constexpr size_t OFF_WDRT  = OFF_WIHT + (size_t)3072 * 288 / 2;   // u16 2048x1280
constexpr size_t OFF_E1T   = OFF_WDRT + (size_t)2048 * 1280 / 2;  // u16 1024x512
constexpr size_t OFF_E2T   = OFF_E1T + (size_t)1024 * 512 / 2;    // u16 1024x1024
constexpr size_t OFF_PET   = OFF_E2T + (size_t)1024 * 1024 / 2;   // u16 512x1024
constexpr size_t OFF_DW2T  = OFF_PET + (size_t)512 * 1024 / 2;    // u16 512x1024
constexpr size_t OFF_BDR   = OFF_DW2T + (size_t)512 * 1024 / 2;   // f32 2048
constexpr size_t OFF_G     = OFF_BDR + 2048;                      // f32 256x3072
constexpr size_t OFF_H     = OFF_G + (size_t)NB * 3072;           // f32 256x1024
constexpr size_t OFF_HB    = OFF_H + (size_t)NB * 1024;           // u16 256x1024
constexpr size_t OFF_ACC   = OFF_HB + (size_t)NB * 1024 / 2;      // f32 16
constexpr size_t OFF_BAR   = OFF_ACC + 16;                        // u32 256 slots
constexpr size_t OFF_XBUF  = OFF_BAR + 256;                       // u16 256x288

__device__ __forceinline__ ushort f2bf(float f) {
  unsigned int u = __float_as_uint(f);
  unsigned int r = (u + 0x7fffu + ((u >> 16) & 1u)) >> 16;
  return (ushort)r;
}
__device__ __forceinline__ float bf2f(ushort u) {
  return __uint_as_float((unsigned int)u << 16);
}

// Contention-free grid barrier: per-block monotonic slot stores (no RMW);
// thread j polls slot j. Requires gridDim.x == blockDim.x == 256.
__device__ __forceinline__ void grid_barrier(unsigned* slots, unsigned step) {
  __syncthreads();
  if (threadIdx.x == 0) {
    __builtin_amdgcn_fence(__ATOMIC_RELEASE, "agent");
    __hip_atomic_store(&slots[blockIdx.x], step, __ATOMIC_RELAXED,
                       __HIP_MEMORY_SCOPE_AGENT);
  }
  while (__hip_atomic_load(&slots[threadIdx.x], __ATOMIC_RELAXED,
                           __HIP_MEMORY_SCOPE_AGENT) < step) {}
  __syncthreads();
  __builtin_amdgcn_fence(__ATOMIC_ACQUIRE, "agent");
}

__global__ void zero_kernel(float* p, int n) {
  int i = blockIdx.x * 256 + threadIdx.x;
  if (i < n) p[i] = 0.f;
}

__global__ void f2bf_kernel(const float* __restrict__ in, ushort* __restrict__ out, int n) {
  int i = blockIdx.x * 256 + threadIdx.x;
  if (i < n) out[i] = f2bf(in[i]);
}

// WHT[n][k]. n<1024: latent-permuted — quad q=(n>>4)&3 selects pm/pl/qm/ql,
// s = (n>>6)*16 + (n&15). n>=1024: whh[n-1024][k].
__global__ void build_wht(const float* __restrict__ prior_w, const float* __restrict__ post_w,
                          const float* __restrict__ whh, ushort* __restrict__ out) {
  int idx = blockIdx.x * 256 + threadIdx.x;  // 4096*1024
  int n = idx >> 10, k = idx & 1023;
  float v;
  if (n < 1024) {
    int q = (n >> 4) & 3;
    int s = ((n >> 6) << 4) | (n & 15);
    v = (q == 0) ? prior_w[k * 512 + s]
      : (q == 1) ? prior_w[k * 512 + 256 + s]
      : (q == 2) ? post_w[k * 512 + s]
                 : post_w[k * 512 + 256 + s];
  } else {
    v = whh[(size_t)(n - 1024) * 1024 + k];
  }
  out[idx] = f2bf(v);
}

// out[c*ldo + r] = bf16(in[r*ldi + c]); grid (C/32, R/32)
__global__ void trans_conv(const float* __restrict__ in, ushort* __restrict__ out,
                           int ldi, int ldo) {
  __shared__ float tile[32][33];
  int r0 = blockIdx.y * 32, c0 = blockIdx.x * 32;
  int tx = threadIdx.x & 31, ty = threadIdx.x >> 5;
#pragma unroll
  for (int p = 0; p < 4; ++p)
    tile[ty + p * 8][tx] = in[(size_t)(r0 + ty + p * 8) * ldi + c0 + tx];
  __syncthreads();
#pragma unroll
  for (int p = 0; p < 4; ++p)
    out[(size_t)(c0 + ty + p * 8) * ldo + r0 + tx] = f2bf(tile[tx][ty + p * 8]);
}

__global__ void build_bdr(const float* __restrict__ dec_b1, const float* __restrict__ rew_b1,
                          float* __restrict__ bdr) {
  int i = blockIdx.x * 256 + threadIdx.x;  // 2048
  bdr[i] = (i < 1024) ? dec_b1[i] : rew_b1[i - 1024];
}

// ---------------------------------------------------------------------------
// Phase A/C bf16 GEMM: C[M,N] = A @ B; A bf16 [M][K], BT bf16 [N][K].
// 64x64 tile, 4 waves, BK=32, LDS stride 40.
// EPI: 1 = +bias, relu, store bf16; 2 = +bias, store f32.
// ---------------------------------------------------------------------------
template <int EPI>
__global__ __launch_bounds__(256) void gemm_bf16(
    const ushort* __restrict__ A, const ushort* __restrict__ BT,
    const float* __restrict__ bias, void* __restrict__ Cv,
    int K, int lda, int ldb, int ldc) {
  __shared__ __align__(16) ushort As[64 * 40];
  __shared__ __align__(16) ushort Bs[64 * 40];
  int tid = threadIdx.x;
  int wave = tid >> 6, lane = tid & 63;
  int quad = lane >> 4, l15 = lane & 15;
  int m0 = blockIdx.y * 64, n0 = blockIdx.x * 64;
  int sr = tid >> 2, sc = (tid & 3) * 8;
  f32x4 acc[4] = {};
  for (int k0 = 0; k0 < K; k0 += 32) {
    *(int4*)&As[sr * 40 + sc] = *(const int4*)(A + (size_t)(m0 + sr) * lda + k0 + sc);
    *(int4*)&Bs[sr * 40 + sc] = *(const int4*)(BT + (size_t)(n0 + sr) * ldb + k0 + sc);
    __syncthreads();
    short8 a = *(const short8*)&As[(wave * 16 + l15) * 40 + quad * 8];
#pragma unroll
    for (int c = 0; c < 4; ++c) {
      short8 b = *(const short8*)&Bs[(c * 16 + l15) * 40 + quad * 8];
      acc[c] = __builtin_amdgcn_mfma_f32_16x16x32_bf16(a, b, acc[c], 0, 0, 0);
    }
    __syncthreads();
  }
#pragma unroll
  for (int c = 0; c < 4; ++c) {
#pragma unroll
    for (int r = 0; r < 4; ++r) {
      size_t row = m0 + wave * 16 + quad * 4 + r;
      int col = n0 + c * 16 + l15;
      float v = acc[c][r] + bias[col];
      if (EPI == 1) v = fmaxf(v, 0.f);
      if (EPI == 1) ((ushort*)Cv)[row * ldc + col] = f2bf(v);
      else ((float*)Cv)[row * ldc + col] = v;
    }
  }
}

// Encoder layer 1 with fused f32->bf16 A staging. A = obs f32 [M][512],
// BT = E1T [1024][512]. M=16128. grid (16, 252). relu, bf16 out.
__global__ __launch_bounds__(256) void gemm_obs(
    const float* __restrict__ A, const ushort* __restrict__ BT,
    const float* __restrict__ bias, ushort* __restrict__ C) {
  __shared__ __align__(16) ushort As[64 * 40];
  __shared__ __align__(16) ushort Bs[64 * 40];
  int tid = threadIdx.x;
  int wave = tid >> 6, lane = tid & 63;
  int quad = lane >> 4, l15 = lane & 15;
  int m0 = blockIdx.y * 64, n0 = blockIdx.x * 64;
  int sr = tid >> 2, sc = (tid & 3) * 8;
  f32x4 acc[4] = {};
  for (int k0 = 0; k0 < 512; k0 += 32) {
    float4 f0 = *(const float4*)(A + (size_t)(m0 + sr) * 512 + k0 + sc);
    float4 f1 = *(const float4*)(A + (size_t)(m0 + sr) * 512 + k0 + sc + 4);
    union { int4 v; ushort u[8]; } cvt;
    cvt.u[0] = f2bf(f0.x); cvt.u[1] = f2bf(f0.y); cvt.u[2] = f2bf(f0.z); cvt.u[3] = f2bf(f0.w);
    cvt.u[4] = f2bf(f1.x); cvt.u[5] = f2bf(f1.y); cvt.u[6] = f2bf(f1.z); cvt.u[7] = f2bf(f1.w);
    *(int4*)&As[sr * 40 + sc] = cvt.v;
    *(int4*)&Bs[sr * 40 + sc] = *(const int4*)(BT + (size_t)(n0 + sr) * 512 + k0 + sc);
    __syncthreads();
    short8 a = *(const short8*)&As[(wave * 16 + l15) * 40 + quad * 8];
#pragma unroll
    for (int c = 0; c < 4; ++c) {
      short8 b = *(const short8*)&Bs[(c * 16 + l15) * 40 + quad * 8];
      acc[c] = __builtin_amdgcn_mfma_f32_16x16x32_bf16(a, b, acc[c], 0, 0, 0);
    }
    __syncthreads();
  }
#pragma unroll
  for (int c = 0; c < 4; ++c) {
#pragma unroll
    for (int r = 0; r < 4; ++r) {
      size_t row = m0 + wave * 16 + quad * 4 + r;
      int col = n0 + c * 16 + l15;
      float v = fmaxf(acc[c][r] + bias[col], 0.f);
      C[row * 1024 + col] = f2bf(v);
    }
  }
}

// ---------------------------------------------------------------------------
// Stage A body: one 64x64 tile of G = HB @ WHT (M=256,N=4096,K=1024), BK=64,
// register prefetch. bx<16 -> latent-permuted cols, fused z/KL epilogue
// (block-reduced KL, 1 atomic/block); else store gh to G [256][3072] f32.
// smem >= 2*64*72 ushorts.
// ---------------------------------------------------------------------------
__device__ __forceinline__ void stage_a_body(
    int t, int bx, int by, ushort* smem,
    const ushort* __restrict__ HB, const ushort* __restrict__ WHT,
    const float* __restrict__ prior_b, const float* __restrict__ poste,
    const float* __restrict__ eps, const float* __restrict__ actions,
    float* __restrict__ G, ushort* __restrict__ xbuf,
    ushort* __restrict__ featc, float* __restrict__ acc_kl) {
  ushort* As = smem;            // 64x72
  ushort* Bs = smem + 64 * 72;  // 64x72
  int tid = threadIdx.x;
  int wave = tid >> 6, lane = tid & 63;
  int quad = lane >> 4, l15 = lane & 15;
  int m0 = by * 64, n0 = bx * 64;
  int sr = tid >> 2, sc = (tid & 3) * 16;
  const ushort* agp = HB + (size_t)(m0 + sr) * 1024 + sc;
  const ushort* bgp = WHT + (size_t)(n0 + sr) * 1024 + sc;
  int4 a0 = *(const int4*)agp, a1 = *(const int4*)(agp + 8);
  int4 b0 = *(const int4*)bgp, b1 = *(const int4*)(bgp + 8);
  f32x4 acc[4] = {};
  for (int k0 = 0;;) {
    *(int4*)&As[sr * 72 + sc] = a0; *(int4*)&As[sr * 72 + sc + 8] = a1;
    *(int4*)&Bs[sr * 72 + sc] = b0; *(int4*)&Bs[sr * 72 + sc + 8] = b1;
    __syncthreads();
    int kn = k0 + 64;
    if (kn < 1024) {
      a0 = *(const int4*)(agp + kn); a1 = *(const int4*)(agp + kn + 8);
      b0 = *(const int4*)(bgp + kn); b1 = *(const int4*)(bgp + kn + 8);
    }
#pragma unroll
    for (int kk = 0; kk < 2; ++kk) {
      short8 a = *(const short8*)&As[(wave * 16 + l15) * 72 + kk * 32 + quad * 8];
#pragma unroll
      for (int c = 0; c < 4; ++c) {
        short8 b = *(const short8*)&Bs[(c * 16 + l15) * 72 + kk * 32 + quad * 8];
        acc[c] = __builtin_amdgcn_mfma_f32_16x16x32_bf16(a, b, acc[c], 0, 0, 0);
      }
    }
    k0 = kn;
    if (k0 >= 1024) break;
    __syncthreads();
  }
  if (bx < 16) {
    int s = (n0 >> 2) + l15;
    float kl_sum = 0.f;
#pragma unroll
    for (int r = 0; r < 4; ++r) {
      int b = m0 + wave * 16 + quad * 4 + r;
      size_t row = (size_t)t * NB + b;
      float pm = acc[0][r] + prior_b[s];
      float pl = acc[1][r] + prior_b[256 + s];
      float qm = acc[2][r] + poste[row * 512 + s];
      float ql = acc[3][r] + poste[row * 512 + 256 + s];
      float e = eps[row * 256 + s];
      float z = qm + e * expf(ql);
      xbuf[b * 288 + s] = f2bf(z);
      featc[(size_t)(t * NB + b) * 1280 + 1024 + s] = f2bf(z);
      if (s < NACT) xbuf[b * 288 + 256 + s] = f2bf(actions[row * NACT + s]);
      float vq = expf(2.f * ql), vp = expf(2.f * pl);
      float dm = qm - pm;
      kl_sum += pl - ql + (vq + dm * dm) / (vp + 1e-8f) - 1.f;
    }
    for (int off = 32; off > 0; off >>= 1) kl_sum += __shfl_down(kl_sum, off);
    __syncthreads();
    float* kls = (float*)smem;
    if (lane == 0) kls[wave] = kl_sum;
    __syncthreads();
    if (tid == 0)
      atomicAdd(acc_kl, 0.5f * (kls[0] + kls[1] + kls[2] + kls[3]));
  } else {
    int ng = n0 - 1024;
#pragma unroll
    for (int c = 0; c < 4; ++c)
#pragma unroll
      for (int r = 0; r < 4; ++r) {
        int b = m0 + wave * 16 + quad * 4 + r;
        G[(size_t)b * 3072 + ng + c * 16 + l15] = acc[c][r];
      }
  }
}

// ---------------------------------------------------------------------------
// Stage B body: GI = xbuf @ WIHT — one block computes all 3 gates for its
// 64-col slice (j in [0,1024)), fused GRU gate epilogue. bx in [0,16),
// by in [0,4). smem >= 4*64*40 ushorts.
// ---------------------------------------------------------------------------
__device__ __forceinline__ void stage_b_body(
    int t, int bx, int by, ushort* smem,
    const ushort* __restrict__ xbuf, const ushort* __restrict__ WIHT,
    const float* __restrict__ G, const float* __restrict__ bih,
    const float* __restrict__ bhh, const unsigned char* __restrict__ dones,
    float* __restrict__ H, ushort* __restrict__ HB, ushort* __restrict__ featc) {
  ushort* As  = smem;             // 64x40
  ushort* Bs0 = smem + 2560;
  ushort* Bs1 = smem + 2 * 2560;
  ushort* Bs2 = smem + 3 * 2560;
  int tid = threadIdx.x;
  int wave = tid >> 6, lane = tid & 63;
  int quad = lane >> 4, l15 = lane & 15;
  int m0 = by * 64, n0 = bx * 64;
  int sr = tid >> 2, sc = (tid & 3) * 8;
  const ushort* agp = xbuf + (size_t)(m0 + sr) * 288 + sc;
  const ushort* bgp0 = WIHT + (size_t)(n0 + sr) * 288 + sc;
  int4 pa = *(const int4*)agp;
  int4 pb0 = *(const int4*)bgp0;
  int4 pb1 = *(const int4*)(bgp0 + (size_t)1024 * 288);
  int4 pb2 = *(const int4*)(bgp0 + (size_t)2048 * 288);
  f32x4 accv[3][4] = {};
  for (int k0 = 0;;) {
    *(int4*)&As[sr * 40 + sc]  = pa;
    *(int4*)&Bs0[sr * 40 + sc] = pb0;
    *(int4*)&Bs1[sr * 40 + sc] = pb1;
    *(int4*)&Bs2[sr * 40 + sc] = pb2;
    __syncthreads();
    int kn = k0 + 32;
    if (kn < 288) {
      pa  = *(const int4*)(agp + kn);
      pb0 = *(const int4*)(bgp0 + kn);
      pb1 = *(const int4*)(bgp0 + (size_t)1024 * 288 + kn);
      pb2 = *(const int4*)(bgp0 + (size_t)2048 * 288 + kn);
    }
    short8 a = *(const short8*)&As[(wave * 16 + l15) * 40 + quad * 8];
#pragma unroll
    for (int c = 0; c < 4; ++c) {
      short8 b0v = *(const short8*)&Bs0[(c * 16 + l15) * 40 + quad * 8];
      accv[0][c] = __builtin_amdgcn_mfma_f32_16x16x32_bf16(a, b0v, accv[0][c], 0, 0, 0);
      short8 b1v = *(const short8*)&Bs1[(c * 16 + l15) * 40 + quad * 8];
      accv[1][c] = __builtin_amdgcn_mfma_f32_16x16x32_bf16(a, b1v, accv[1][c], 0, 0, 0);
      short8 b2v = *(const short8*)&Bs2[(c * 16 + l15) * 40 + quad * 8];
      accv[2][c] = __builtin_amdgcn_mfma_f32_16x16x32_bf16(a, b2v, accv[2][c], 0, 0, 0);
    }
    k0 = kn;
    if (k0 >= 288) break;
    __syncthreads();
  }
#pragma unroll
  for (int c = 0; c < 4; ++c) {
#pragma unroll
    for (int r = 0; r < 4; ++r) {
      int b_idx = m0 + wave * 16 + quad * 4 + r;
      int j = n0 + c * 16 + l15;
      const float* gp = G + (size_t)b_idx * 3072;
      float ir = accv[0][c][r] + bih[j];
      float iz = accv[1][c][r] + bih[1024 + j];
      float in_ = accv[2][c][r] + bih[2048 + j];
      float hr = gp[j] + bhh[j];
      float hz = gp[1024 + j] + bhh[1024 + j];
      float hn = gp[2048 + j] + bhh[2048 + j];
      float rg = 1.f / (1.f + expf(-(ir + hr)));
      float u = 1.f / (1.f + expf(-(iz + hz)));
      float n = tanhf(in_ + rg * hn);
      float hprev = H[b_idx * 1024 + j];
      float hnext = (1.f - u) * n + u * hprev;
      featc[(size_t)(t * NB + b_idx) * 1280 + j] = f2bf(hnext);
      float mask = 1.f - (float)dones[t * NB + b_idx];
      float hm = hnext * mask;
      H[b_idx * 1024 + j] = hm;
      HB[b_idx * 1024 + j] = f2bf(hm);
    }
  }
}

// ---------------------------------------------------------------------------
// Persistent Phase-B kernel: all 63 steps, slot-array barriers.
// Grid 256 x 256 (1 block/CU). 125 barriers (last elided — kernel end).
// ---------------------------------------------------------------------------
__global__ __launch_bounds__(256) void phase_b_all(
    const ushort* __restrict__ WHT, const ushort* __restrict__ WIHT,
    const float* __restrict__ prior_b, const float* __restrict__ poste,
    const float* __restrict__ eps, const float* __restrict__ actions,
    const float* __restrict__ bih, const float* __restrict__ bhh,
    const unsigned char* __restrict__ dones,
    float* __restrict__ G, float* __restrict__ H, ushort* __restrict__ HB,
    ushort* __restrict__ xbuf, ushort* __restrict__ featc,
    float* __restrict__ acc_kl, unsigned* __restrict__ slots) {
  __shared__ __align__(16) ushort smem[10240];  // 20 KB shared by both stages
  unsigned barix = 0;
  for (int t = 0; t < TSTEPS; ++t) {
    stage_a_body(t, blockIdx.x & 63, blockIdx.x >> 6, smem,
                 HB, WHT, prior_b, poste, eps, actions, G, xbuf, featc, acc_kl);
    grid_barrier(slots, ++barix);
    if (blockIdx.x < 64) {
      stage_b_body(t, blockIdx.x & 15, blockIdx.x >> 4, smem,
                   xbuf, WIHT, G, bih, bhh, dones, H, HB, featc);
    }
    if (t + 1 < TSTEPS) grid_barrier(slots, ++barix);
  }
}

// Standalone fallback kernels (per-step launches, known-good)
__global__ __launch_bounds__(256) void step_g_kernel(
    int t, const ushort* __restrict__ HB, const ushort* __restrict__ WHT,
    const float* __restrict__ prior_b, const float* __restrict__ poste,
    const float* __restrict__ eps, const float* __restrict__ actions,
    float* __restrict__ G, ushort* __restrict__ xbuf,
    ushort* __restrict__ featc, float* __restrict__ acc_kl) {
  __shared__ __align__(16) ushort smem[2 * 64 * 72];
  stage_a_body(t, blockIdx.x, blockIdx.y, smem,
               HB, WHT, prior_b, poste, eps, actions, G, xbuf, featc, acc_kl);
}

__global__ __launch_bounds__(256) void gru_step_kernel(
    int t, const ushort* __restrict__ xbuf, const ushort* __restrict__ WIHT,
    const float* __restrict__ G, const float* __restrict__ bih,
    const float* __restrict__ bhh, const unsigned char* __restrict__ dones,
    float* __restrict__ H, ushort* __restrict__ HB, ushort* __restrict__ featc) {
  __shared__ __align__(16) ushort smem[4 * 64 * 40];
  stage_b_body(t, blockIdx.x, blockIdx.y, smem,
               xbuf, WIHT, G, bih, bhh, dones, H, HB, featc);
}

// ---------------------------------------------------------------------------
// Decoder-out GEMM + fused recon loss. A = DR1 bf16 cols 0:1024 (lda 2048),
// BT = DW2T [512][1024]. M=16128, N=512, K=1024. grid (8, 252).
// ---------------------------------------------------------------------------
__global__ __launch_bounds__(256) void decobs_loss_kernel(
    const ushort* __restrict__ A, const ushort* __restrict__ BT,
    const float* __restrict__ bias, const float* __restrict__ obs_next,
    float* __restrict__ acc) {
  __shared__ __align__(16) ushort As[64 * 40];
  __shared__ __align__(16) ushort Bs[64 * 40];
  int tid = threadIdx.x;
  int wave = tid >> 6, lane = tid & 63;
  int quad = lane >> 4, l15 = lane & 15;
  int m0 = blockIdx.y * 64, n0 = blockIdx.x * 64;
  int sr = tid >> 2, sc = (tid & 3) * 8;
  f32x4 accm[4] = {};
  for (int k0 = 0; k0 < 1024; k0 += 32) {
    *(int4*)&As[sr * 40 + sc] = *(const int4*)(A + (size_t)(m0 + sr) * 2048 + k0 + sc);
    *(int4*)&Bs[sr * 40 + sc] = *(const int4*)(BT + (size_t)(n0 + sr) * 1024 + k0 + sc);
    __syncthreads();
    short8 a = *(const short8*)&As[(wave * 16 + l15) * 40 + quad * 8];
#pragma unroll
    for (int c = 0; c < 4; ++c) {
      short8 b = *(const short8*)&Bs[(c * 16 + l15) * 40 + quad * 8];
      accm[c] = __builtin_amdgcn_mfma_f32_16x16x32_bf16(a, b, accm[c], 0, 0, 0);
    }
    __syncthreads();
  }
  float local = 0.f;
#pragma unroll
  for (int c = 0; c < 4; ++c) {
#pragma unroll
    for (int r = 0; r < 4; ++r) {
      size_t row = m0 + wave * 16 + quad * 4 + r;
      int col = n0 + c * 16 + l15;
      float v = accm[c][r] + bias[col];
      float d = v - obs_next[row * 512 + col];
      local += d * d;
    }
  }
  __shared__ float red[256];
  red[tid] = local;
  __syncthreads();
  for (int st = 128; st > 0; st >>= 1) {
    if (tid < st) red[tid] += red[tid + st];
    __syncthreads();
  }
  if (tid == 0) atomicAdd(&acc[0], red[0]);
}

// Reward matvec + loss. R1 = DR1 + 1024 (bf16, row stride 2048).
__global__ __launch_bounds__(256) void rew_loss_kernel(
    const ushort* __restrict__ R1, const float* __restrict__ w2,
    const float* __restrict__ b2, const float* __restrict__ rewards,
    float* __restrict__ acc) {
  int wave = threadIdx.x >> 6;
  int lane = threadIdx.x & 63;
  int row = blockIdx.x * 4 + wave;
  const ushort* rp = R1 + (size_t)row * 2048;
  float s = 0.f;
#pragma unroll
  for (int i = 0; i < 16; ++i) s += bf2f(rp[lane + 64 * i]) * w2[lane + 64 * i];
  for (int off = 32; off > 0; off >>= 1) s += __shfl_down(s, off);
  if (lane == 0) {
    float d = s + b2[0] - rewards[row];
    atomicAdd(&acc[1], d * d);
  }
}

__global__ void finalize_kernel(const float* __restrict__ acc, float* __restrict__ out) {
  float recon = acc[0] / ((float)NROWS * 512.f);
  float rew = acc[1] / (float)NROWS;
  float kl = acc[2] / (float)NROWS;
  out[0] = recon + rew + kl;
  out[1] = recon;
  out[2] = rew;
  out[3] = kl;
}

}  // namespace

extern "C" void kernel_launch(void* const* d_in, const int* in_sizes, int n_in,
                              void* d_out, int out_size, void* d_ws, size_t ws_size,
                              hipStream_t stream) {
  const float* obs     = (const float*)d_in[0];
  const float* actions = (const float*)d_in[1];
  const float* rewards = (const float*)d_in[2];
  const unsigned char* dones = (const unsigned char*)d_in[3];
  const float* eps     = (const float*)d_in[4];
  const float* enc_w1  = (const float*)d_in[5];
  const float* enc_b1  = (const float*)d_in[6];
  const float* enc_w2  = (const float*)d_in[7];
  const float* enc_b2  = (const float*)d_in[8];
  const float* gru_wih = (const float*)d_in[9];
  const float* gru_whh = (const float*)d_in[10];
  const float* gru_bih = (const float*)d_in[11];
  const float* gru_bhh = (const float*)d_in[12];
  const float* prior_w = (const float*)d_in[13];
  const float* prior_b = (const float*)d_in[14];
  const float* post_w  = (const float*)d_in[15];
  const float* post_b  = (const float*)d_in[16];
  const float* dec_w1  = (const float*)d_in[17];
  const float* dec_b1  = (const float*)d_in[18];
  const float* dec_w2  = (const float*)d_in[19];
  const float* dec_b2  = (const float*)d_in[20];
  const float* rew_w1  = (const float*)d_in[21];
  const float* rew_b1  = (const float*)d_in[22];
  const float* rew_w2  = (const float*)d_in[23];
  const float* rew_b2  = (const float*)d_in[24];
  float* out = (float*)d_out;
  float* ws = (float*)d_ws;

  float*  POSTE = ws + OFF_POSTE;
  ushort* E1    = (ushort*)(ws + OFF_E1);
  ushort* EMB   = (ushort*)(ws + OFF_EMB);
  ushort* DR1   = (ushort*)(ws + OFF_DR1);
  ushort* FEAT  = (ushort*)(ws + OFF_FEAT);
  ushort* WHT   = (ushort*)(ws + OFF_WHT);
  ushort* WIHT  = (ushort*)(ws + OFF_WIHT);
  ushort* WDRT  = (ushort*)(ws + OFF_WDRT);
  ushort* E1T   = (ushort*)(ws + OFF_E1T);
  ushort* E2T   = (ushort*)(ws + OFF_E2T);
  ushort* PET   = (ushort*)(ws + OFF_PET);
  ushort* DW2T  = (ushort*)(ws + OFF_DW2T);
  float*  BDR   = ws + OFF_BDR;
  float*  G     = ws + OFF_G;
  float*  H     = ws + OFF_H;
  ushort* HB    = (ushort*)(ws + OFF_HB);
  float*  ACC   = ws + OFF_ACC;
  unsigned* BAR = (unsigned*)(ws + OFF_BAR);
  ushort* XBUF  = (ushort*)(ws + OFF_XBUF);

  // Phase 0: zero H + HB + ACC + BAR (contiguous), build bf16 weights
  {
    int nzero = NB * 1024 + NB * 512 + 16 + 256;  // H + HB + ACC + BAR
    zero_kernel<<<(nzero + 255) / 256, 256, 0, stream>>>(H, nzero);
  }
  build_wht<<<4096 * 1024 / 256, 256, 0, stream>>>(prior_w, post_w, gru_whh, WHT);
  f2bf_kernel<<<(3072 * 288) / 256, 256, 0, stream>>>(gru_wih, WIHT, 3072 * 288);
  trans_conv<<<dim3(1024 / 32, 1280 / 32), 256, 0, stream>>>(dec_w1, WDRT, 1024, 1280);
  trans_conv<<<dim3(1024 / 32, 1280 / 32), 256, 0, stream>>>(rew_w1, WDRT + (size_t)1024 * 1280, 1024, 1280);
  trans_conv<<<dim3(1024 / 32, 512 / 32), 256, 0, stream>>>(enc_w1, E1T, 1024, 512);
  trans_conv<<<dim3(1024 / 32, 1024 / 32), 256, 0, stream>>>(enc_w2, E2T, 1024, 1024);
  trans_conv<<<dim3(512 / 32, 1024 / 32), 256, 0, stream>>>(post_w + (size_t)1024 * 512, PET, 512, 1024);
  trans_conv<<<dim3(512 / 32, 1024 / 32), 256, 0, stream>>>(dec_w2, DW2T, 512, 1024);
  build_bdr<<<8, 256, 0, stream>>>(dec_b1, rew_b1, BDR);

  // Phase A: encoder + posterior-from-emb, full-size (3 launches)
  gemm_obs<<<dim3(16, NROWS / 64), 256, 0, stream>>>(obs, E1T, enc_b1, E1);
  gemm_bf16<1><<<dim3(16, NROWS / 64), 256, 0, stream>>>(
      E1, E2T, enc_b2, EMB, 1024, 1024, 1024, 1024);
  gemm_bf16<2><<<dim3(8, NROWS / 64), 256, 0, stream>>>(
      EMB, PET, post_b, POSTE, 1024, 1024, 1024, 512);

  // Phase B: single persistent launch (all 63 steps), slot-barrier sync.
  {
    float* acc_kl = &ACC[2];
    unsigned* slots = BAR;
    const ushort* wht = WHT; const ushort* wiht = WIHT;
    void* args[] = {&wht, &wiht, &prior_b, &POSTE, &eps, &actions,
                    &gru_bih, &gru_bhh, &dones, &G, &H, &HB, &XBUF, &FEAT,
                    &acc_kl, &slots};
    hipError_t cerr = hipLaunchCooperativeKernel(
        (const void*)phase_b_all, dim3(256), dim3(256), args, 0, stream);
    if (cerr != hipSuccess) {
      for (int t = 0; t < TSTEPS; ++t) {
        step_g_kernel<<<dim3(64, 4), 256, 0, stream>>>(
            t, HB, WHT, prior_b, POSTE, eps, actions, G, XBUF, FEAT, &ACC[2]);
        gru_step_kernel<<<dim3(16, 4), 256, 0, stream>>>(
            t, XBUF, WIHT, G, gru_bih, gru_bhh, dones, H, HB, FEAT);
      }
    }
  }

  // Phase C: heads + losses, full-size (DR1 aliases E1+EMB — both dead now)
  gemm_bf16<1><<<dim3(32, NROWS / 64), 256, 0, stream>>>(
      FEAT, WDRT, BDR, DR1, 1280, 1280, 1280, 2048);
  decobs_loss_kernel<<<dim3(8, NROWS / 64), 256, 0, stream>>>(
      DR1, DW2T, dec_b2, obs + (size_t)NB * 512, ACC);
  rew_loss_kernel<<<NROWS / 4, 256, 0, stream>>>(
      DR1 + 1024, rew_w2, rew_b2, rewards, ACC);

  finalize_kernel<<<1, 1, 0, stream>>>(ACC, out);
}